// Round 8
// baseline (133.380 us; speedup 1.0000x reference)
//
#include <hip/hip_runtime.h>
#include <hip/hip_bf16.h>
#include <cstdint>

#define CC 128
#define NN 6400
#define NAa 1600
#define HEADS 4
#define HD 32
#define MT 64

#define P_ROW 68
#define P_HEAD 1096   // 16*68+8 pad
#define A_ROW 76
#define A_HEAD 1224   // 16*76+8 pad
#define PW (HEADS * P_HEAD)   // 4384 elems
#define AW (HEADS * A_HEAD)   // 4896 elems
// halo buffer: [parity][h][lo][4] bf16
#define HB_IDX(par, hh, lo) ((((par)*4 + (hh))*16 + (lo)) * 4)
#define XROW 136              // qkv LDS x-tile row stride (16B-aligned: 272 B)

typedef __attribute__((ext_vector_type(8))) short bfrag8;
typedef __attribute__((ext_vector_type(4))) float ffrag4;
typedef union { uint2 u2[2]; bfrag8 f8; } cvt16;

#define LOG2E 1.4426950408889634f
#define QSCL (0.17677669529663687f * 1.4426950408889634f)

__device__ __forceinline__ float sigmoid_fast(float y) {
  return __builtin_amdgcn_rcpf(1.0f + __builtin_amdgcn_exp2f(-LOG2E * y));
}
__device__ __forceinline__ unsigned short f2bf(float f) {
  unsigned u = __float_as_uint(f);
  return (unsigned short)((u + 0x7FFFu + ((u >> 16) & 1u)) >> 16);
}
// packed 2xf32 -> 2xbf16 (RNE) — should emit v_cvt_pk_bf16_f32
__device__ __forceinline__ unsigned pk2(float a, float b) {
  float2 f2; f2.x = a; f2.y = b;
  __hip_bfloat162 h = __float22bfloat162_rn(f2);
  union { __hip_bfloat162 h2; unsigned u; } cv; cv.h2 = h;
  return cv.u;
}
__device__ __forceinline__ float bfl(unsigned u) { return __uint_as_float(u << 16); }
__device__ __forceinline__ float bfh(unsigned u) { return __uint_as_float(u & 0xFFFF0000u); }

// ---- K0: prep — weights->bf16 with scales folded (x-transpose fused into qkv) ----
__global__ __launch_bounds__(256) void prep_kernel(
    const float* __restrict__ w_qk, const float* __restrict__ s_qk,
    const float* __restrict__ w_in, const float* __restrict__ s_in,
    const float* __restrict__ w_out, const float* __restrict__ s_out,
    unsigned short* __restrict__ wqkb, unsigned short* __restrict__ wob) {
  const int blk = blockIdx.x, tid = threadIdx.x;
  if (blk < 8) {
    const int r0 = blk * 48;
    for (int i = tid; i < 6144; i += 256) {
      int r = r0 + (i >> 7), c = i & 127;
      float wv, sv;
      if (r < 2 * CC) { wv = w_qk[r * CC + c]; sv = s_qk[r] * (r < CC ? QSCL : 1.0f); }
      else           { wv = w_in[(r - 2 * CC) * CC + c]; sv = s_in[r - 2 * CC]; }
      wqkb[r * CC + c] = f2bf(wv * sv);
    }
  } else {
    const int r0 = (blk - 8) * 64;
    for (int i = tid; i < 8192; i += 256) {
      int r = r0 + (i >> 7), c = i & 127;
      wob[r * CC + c] = f2bf(w_out[r * CC + c] * s_out[r]);
    }
  }
}

// ---- K1: qkv as MFMA GEMM (384 x 6400 x K=128), x transposed in-block via LDS ----
__global__ __launch_bounds__(256) void qkv_kernel(
    const float* __restrict__ x, const unsigned short* __restrict__ wqkb,
    const float* __restrict__ t_qk, const float* __restrict__ t_in,
    unsigned short* __restrict__ qt, unsigned short* __restrict__ kt,
    unsigned short* __restrict__ vb) {
  __shared__ __align__(16) unsigned short xb[16 * XROW];  // 4352 B
  const int tid = threadIdx.x;
  const int w = tid >> 6, lane = tid & 63, lo = lane & 15, g = lane >> 4;
  const int blk = blockIdx.x;
  const int b = blk / 400, pt = blk - b * 400;
  const int ng0 = pt * 16;
  const int a = ng0 / NAa, na0 = ng0 - a * NAa;
  const int be = b * 4 + a;
  // ---- stage: transpose x[b][c][ng0..ng0+15] f32 -> xb[n][c] bf16 ----
  {
    const int c = tid >> 1, half = tid & 1;
    const float* xr = &x[((size_t)(b * CC + c)) * NN + ng0 + 8 * half];
    const float4 f0 = *(const float4*)xr;
    const float4 f1 = *(const float4*)(xr + 4);
    unsigned short* dst = &xb[(8 * half) * XROW + c];
    dst[0 * XROW] = f2bf(f0.x); dst[1 * XROW] = f2bf(f0.y);
    dst[2 * XROW] = f2bf(f0.z); dst[3 * XROW] = f2bf(f0.w);
    dst[4 * XROW] = f2bf(f1.x); dst[5 * XROW] = f2bf(f1.y);
    dst[6 * XROW] = f2bf(f1.z); dst[7 * XROW] = f2bf(f1.w);
  }
  __syncthreads();
  bfrag8 bf[4];
#pragma unroll
  for (int kk = 0; kk < 4; kk++) bf[kk] = *(const bfrag8*)&xb[lo * XROW + kk * 32 + g * 8];
#pragma unroll
  for (int mt6 = 0; mt6 < 6; mt6++) {
    const int rowbase = (w * 6 + mt6) * 16;
    ffrag4 d = {0.f, 0.f, 0.f, 0.f};
#pragma unroll
    for (int kk = 0; kk < 4; kk++) {
      bfrag8 af = *(const bfrag8*)&wqkb[(size_t)(rowbase + lo) * CC + kk * 32 + g * 8];
      d = __builtin_amdgcn_mfma_f32_16x16x32_bf16(af, bf[kk], d, 0, 0, 0);
    }
    const int r0c = rowbase + 4 * g;
    if (r0c < CC) {
      const int h = r0c >> 5, d0 = r0c & 31;
      uint2 pk;
      pk.x = pk2(d[0] + t_qk[r0c] * QSCL, d[1] + t_qk[r0c + 1] * QSCL);
      pk.y = pk2(d[2] + t_qk[r0c + 2] * QSCL, d[3] + t_qk[r0c + 3] * QSCL);
      *(uint2*)&qt[((size_t)(be * HEADS + h) * NAa + na0 + lo) * HD + d0] = pk;
    } else if (r0c < 2 * CC) {
      const int ch = r0c - CC, h = ch >> 5, d0 = ch & 31;
      uint2 pk;
      pk.x = pk2(d[0] + t_qk[r0c], d[1] + t_qk[r0c + 1]);
      pk.y = pk2(d[2] + t_qk[r0c + 2], d[3] + t_qk[r0c + 3]);
      *(uint2*)&kt[((size_t)(be * HEADS + h) * NAa + na0 + lo) * HD + d0] = pk;
    } else {
      const int ch0 = r0c - 2 * CC;
      const uint2 xv = *(const uint2*)&xb[lo * XROW + ch0];
      float xr[4] = {bfl(xv.x), bfh(xv.x), bfl(xv.y), bfh(xv.y)};
#pragma unroll
      for (int r = 0; r < 4; r++) {
        float y = d[r] + t_in[ch0 + r];
        vb[((size_t)be * CC + ch0 + r) * NAa + na0 + lo] = f2bf(sigmoid_fast(y) * xr[r]);
      }
    }
  }
}

// ---- K2a: partial softmax denominators (M0 = 0, q pre-scaled), 32 q/block ----
__global__ __launch_bounds__(256) void stats_kernel(
    const unsigned short* __restrict__ qt, const unsigned short* __restrict__ kt,
    float* __restrict__ pstats) {
  int tid = threadIdx.x;
  int h = tid >> 6, lane = tid & 63, lo = lane & 15, g = lane >> 4;
  int bid = blockIdx.x;
  int be = bid & 7;
  int rest = bid >> 3;
  int n0 = (rest % 50) * 32;
  int split = rest / 50;
  int ts0 = split ? 12 : 0, ts1 = split ? 25 : 12;

  const unsigned short* qtb = qt + (size_t)(be * HEADS + h) * NAa * HD;
  const unsigned short* ktb = kt + (size_t)(be * HEADS + h) * NAa * HD;

  bfrag8 qf0 = *(const bfrag8*)(qtb + (size_t)(n0 + lo) * HD + g * 8);
  bfrag8 qf1 = *(const bfrag8*)(qtb + (size_t)(n0 + 16 + lo) * HD + g * 8);
  float sm0[4] = {0.f, 0.f, 0.f, 0.f};
  float sm1[4] = {0.f, 0.f, 0.f, 0.f};
  for (int t = ts0; t < ts1; t++) {
    int m0 = t * MT;
#pragma unroll
    for (int sb = 0; sb < 4; sb++) {
      bfrag8 kf = *(const bfrag8*)(ktb + (size_t)(m0 + sb * 16 + lo) * HD + g * 8);
      ffrag4 z = {0.f, 0.f, 0.f, 0.f};
      ffrag4 c0 = __builtin_amdgcn_mfma_f32_16x16x32_bf16(qf0, kf, z, 0, 0, 0);
      ffrag4 c1 = __builtin_amdgcn_mfma_f32_16x16x32_bf16(qf1, kf, z, 0, 0, 0);
#pragma unroll
      for (int r = 0; r < 4; r++) {
        sm0[r] += __builtin_amdgcn_exp2f(c0[r]);
        sm1[r] += __builtin_amdgcn_exp2f(c1[r]);
      }
    }
  }
#pragma unroll
  for (int r = 0; r < 4; r++) {
#pragma unroll
    for (int off = 1; off <= 8; off <<= 1) {
      sm0[r] += __shfl_xor(sm0[r], off);
      sm1[r] += __shfl_xor(sm1[r], off);
    }
  }
  if (lo == 0) {
    float4 s4; s4.x = sm0[0]; s4.y = sm0[1]; s4.z = sm0[2]; s4.w = sm0[3];
    *(float4*)&pstats[((size_t)(split * 8 + be) * HEADS + h) * NAa + n0 + 4 * g] = s4;
    float4 s5; s5.x = sm1[0]; s5.y = sm1[1]; s5.z = sm1[2]; s5.w = sm1[3];
    *(float4*)&pstats[((size_t)(split * 8 + be) * HEADS + h) * NAa + n0 + 16 + 4 * g] = s5;
  }
}

// ---- K2b: apply — 256-THREAD blocks (4 waves = 4 heads, NB=16, u serialized
//      in-wave). LDS 19.6 KB -> 8 blocks/CU at the 32-wave cap: 2x barrier-group
//      diversity, 4-wave barriers, and NO cross-u epilogue reduction (both
//      k-halves accumulate in the same wave's oacc). 3-way key split kept.
//      VGPR must stay <=64 for 8 waves/SIMD (inventory ~59; R3: never force). ----
__global__ __launch_bounds__(256) void apply_kernel(
    const unsigned short* __restrict__ qt, const unsigned short* __restrict__ kt,
    const unsigned short* __restrict__ vb, const float* __restrict__ pstats,
    const float* __restrict__ w_fg, const float* __restrict__ s_fg,
    const float* __restrict__ t_fg, unsigned short* __restrict__ o_part) {
  __shared__ __align__(16) unsigned short Ps[PW];    //  8768 B (cols 0..63 = keys m0..m0+63)
  __shared__ __align__(16) unsigned short A2s[AW];   //  9792 B
  __shared__ __align__(16) unsigned short Hb[512];   //  1024 B halo [par][h][lo][4]
  const int tid = threadIdx.x;
  const int h = tid >> 6, lane = tid & 63, lo = lane & 15, g = lane >> 4;
  const int bid = blockIdx.x;
  const int be = bid & 7;
  const int rest = bid >> 3;
  const int n0 = (rest % 100) * 16;
  const int split = rest / 100;                        // 0..2
  const int ts0 = (split == 0) ? 0 : (split == 1 ? 9 : 17);
  const int tend = (split == 0) ? 9 : (split == 1 ? 17 : 26);  // t=25 virtual tail
  const int p0 = ts0 & 1;

  const unsigned short* qtb = qt + (size_t)(be * HEADS + h) * NAa * HD;
  const unsigned short* ktb = kt + (size_t)(be * HEADS + h) * NAa * HD;
  const unsigned short* vhb = vb + (size_t)(be * CC + h * HD) * NAa;

  const bfrag8 qf = *(const bfrag8*)(qtb + (size_t)(n0 + lo) * HD + g * 8);

  // conv-weight A-fragment (constant): row=lo=(ho*4+s), k=g*8+j
  bfrag8 wfrag;
  {
    const int ho = lo >> 2, s = lo & 3;
#pragma unroll
    for (int j = 0; j < 8; j++) {
      const int tp = j - s;
      float wv = (tp >= 0 && tp < 5) ? w_fg[(ho * HEADS + g) * 5 + tp] : 0.0f;
      wfrag[j] = (short)f2bf(wv);
    }
  }
  const float sfv = s_fg[g], tfv = t_fg[g];

  // -log2(denominator), folded into QK's MFMA accumulator
  const float den = pstats[((size_t)(0 + be) * HEADS + h) * NAa + n0 + lo] +
                    pstats[((size_t)(8 + be) * HEADS + h) * NAa + n0 + lo];
  const float linv = -__log2f(den);
  const ffrag4 cin = {linv, linv, linv, linv};

  ffrag4 oacc0 = {0.f, 0.f, 0.f, 0.f};
  ffrag4 oacc1 = {0.f, 0.f, 0.f, 0.f};

  // ---- prologue: Hb[p0] = halo for conv(ts0) ----
  if (split == 0) {
    if (g == 0) {
      uint2 zz; zz.x = 0; zz.y = 0;
      *(uint2*)&Hb[HB_IDX(p0, h, lo)] = zz;
    }
  } else {
    // halo keys ts0*64-4..-1 from K rows ts0*64-16..-1 (g==3 lanes hold them)
    bfrag8 kf = *(const bfrag8*)(ktb + (size_t)(ts0 * MT - 16 + lo) * HD + g * 8);
    ffrag4 c = __builtin_amdgcn_mfma_f32_16x16x32_bf16(kf, qf, cin, 0, 0, 0);
    if (g == 3) {
      uint2 pk;
      pk.x = pk2(__builtin_amdgcn_exp2f(c[0]), __builtin_amdgcn_exp2f(c[1]));
      pk.y = pk2(__builtin_amdgcn_exp2f(c[2]), __builtin_amdgcn_exp2f(c[3]));
      *(uint2*)&Hb[HB_IDX(p0, h, lo)] = pk;
    }
  }
  // ---- prologue: QK(ts0) -> Ps; sb==3/g==3 lanes also feed Hb[p0^1] ----
  {
    const int m0 = ts0 * MT;
#pragma unroll
    for (int sb = 0; sb < 4; sb++) {
      bfrag8 kf = *(const bfrag8*)(ktb + (size_t)(m0 + sb * 16 + lo) * HD + g * 8);
      ffrag4 c = __builtin_amdgcn_mfma_f32_16x16x32_bf16(kf, qf, cin, 0, 0, 0);
      uint2 pk;
      pk.x = pk2(__builtin_amdgcn_exp2f(c[0]), __builtin_amdgcn_exp2f(c[1]));
      pk.y = pk2(__builtin_amdgcn_exp2f(c[2]), __builtin_amdgcn_exp2f(c[3]));
      *(uint2*)&Ps[h * P_HEAD + lo * P_ROW + 16 * sb + 4 * g] = pk;
      if (sb == 3 && g == 3)
        *(uint2*)&Hb[HB_IDX(p0 ^ 1, h, lo)] = pk;
    }
  }
  __syncthreads();

  for (int t = ts0; t < tend; t++) {
    const int m0 = t * MT;
    const int par = t & 1;
    // early V loads (both u halves) for PV(t)
    bfrag8 vf[2][2];
#pragma unroll
    for (int u = 0; u < 2; ++u) {
      vf[u][0] = *(const bfrag8*)(vhb + (size_t)lo * NAa + (m0 - 2 + 32 * u + 8 * g));
      vf[u][1] = *(const bfrag8*)(vhb + (size_t)(16 + lo) * NAa + (m0 - 2 + 32 * u + 8 * g));
    }
    const bool doqk = (t + 1 < tend);
    const bool realqk = doqk && (t + 1 < 25);
    bfrag8 kfp[4];
    if (realqk) {
      const int m1 = (t + 1) * MT;
#pragma unroll
      for (int sb = 0; sb < 4; sb++)
        kfp[sb] = *(const bfrag8*)(ktb + (size_t)(m1 + sb * 16 + lo) * HD + g * 8);
    }
    // ---- phase 1: conv(t) reads Ps/Hb -> writes A2s; wave h does i=4h..4h+3 ----
    const bool edge = (t == 0) || (t == 25);
#pragma unroll
    for (int ii = 0; ii < 4; ii++) {
      const int i = 4 * h + ii;
      cvt16 bb;
      if (i == 0)
        bb.u2[0] = *(const uint2*)&Hb[HB_IDX(par, g, lo)];
      else
        bb.u2[0] = *(const uint2*)&Ps[g * P_HEAD + lo * P_ROW + 4 * i - 4];
      bb.u2[1] = *(const uint2*)&Ps[g * P_HEAD + lo * P_ROW + 4 * i];
      ffrag4 z = {0.f, 0.f, 0.f, 0.f};
      ffrag4 d = __builtin_amdgcn_mfma_f32_16x16x32_bf16(wfrag, bb.f8, z, 0, 0, 0);
      float a2v[4];
      if (edge) {
#pragma unroll
        for (int r = 0; r < 4; r++) {
          const int mp = m0 - 2 + 4 * i + r;
          float y = d[r] * sfv + tfv;
          float v = y * sigmoid_fast(y);
          a2v[r] = (mp >= 0 && mp < NAa) ? v : 0.0f;
        }
      } else {
#pragma unroll
        for (int r = 0; r < 4; r++) {
          float y = d[r] * sfv + tfv;
          a2v[r] = y * sigmoid_fast(y);
        }
      }
      uint2 pk;
      pk.x = pk2(a2v[0], a2v[1]);
      pk.y = pk2(a2v[2], a2v[3]);
      *(uint2*)&A2s[g * A_HEAD + lo * A_ROW + 4 * i] = pk;
    }
    __syncthreads();
    // ---- phase 2: QK(t+1) -> Ps/Hb, then PV(t) reads A2s ----
    if (doqk) {
      if (realqk) {
#pragma unroll
        for (int sb = 0; sb < 4; sb++) {
          ffrag4 c = __builtin_amdgcn_mfma_f32_16x16x32_bf16(kfp[sb], qf, cin, 0, 0, 0);
          uint2 pk;
          pk.x = pk2(__builtin_amdgcn_exp2f(c[0]), __builtin_amdgcn_exp2f(c[1]));
          pk.y = pk2(__builtin_amdgcn_exp2f(c[2]), __builtin_amdgcn_exp2f(c[3]));
          *(uint2*)&Ps[h * P_HEAD + lo * P_ROW + 16 * sb + 4 * g] = pk;
          if (sb == 3 && g == 3)
            *(uint2*)&Hb[HB_IDX(par, h, lo)] = pk;   // halo for conv(t+2)
        }
      } else {
        uint2 zz; zz.x = 0; zz.y = 0;
#pragma unroll
        for (int sb = 0; sb < 4; sb++)
          *(uint2*)&Ps[h * P_HEAD + lo * P_ROW + 16 * sb + 4 * g] = zz;
      }
    }
    // PV(t): head h, both k-halves accumulate in-wave
#pragma unroll
    for (int u = 0; u < 2; ++u) {
      cvt16 av;
      av.u2[0] = *(const uint2*)&A2s[h * A_HEAD + lo * A_ROW + 32 * u + 8 * g];
      av.u2[1] = *(const uint2*)&A2s[h * A_HEAD + lo * A_ROW + 32 * u + 8 * g + 4];
      oacc0 = __builtin_amdgcn_mfma_f32_16x16x32_bf16(av.f8, vf[u][0], oacc0, 0, 0, 0);
      oacc1 = __builtin_amdgcn_mfma_f32_16x16x32_bf16(av.f8, vf[u][1], oacc1, 0, 0, 0);
    }
    __syncthreads();
  }

  // ---- epilogue: direct register->global write (no cross-wave reduction) ----
#pragma unroll
  for (int r = 0; r < 4; r++) {
    const size_t rowoff = ((size_t)(split * 8 + be) * NAa + n0 + 4 * g + r) * CC;
    o_part[rowoff + h * HD + lo] = f2bf(oacc0[r]);
    o_part[rowoff + h * HD + 16 + lo] = f2bf(oacc1[r]);
  }
}

// ---- K3: out as MFMA GEMM + SiLU-gate + residual (sums 3 o_part splits) ----
__global__ __launch_bounds__(256) void out_kernel(
    const unsigned short* __restrict__ o_part, const unsigned short* __restrict__ wob,
    const float* __restrict__ t_out, const float* __restrict__ x,
    float* __restrict__ out) {
  const int tid = threadIdx.x;
  const int w = tid >> 6, lane = tid & 63, lo = lane & 15, g = lane >> 4;
  const int blk = blockIdx.x;
  const int b = blk / 400, pt = blk - b * 400;
  const int ng0 = pt * 16;
  const int a = ng0 / NAa, na0 = ng0 - a * NAa;
  const int be = b * 4 + a;
  const size_t orow0 = ((size_t)(0 * 8 + be) * NAa + na0 + lo) * CC;
  const size_t orow1 = ((size_t)(1 * 8 + be) * NAa + na0 + lo) * CC;
  const size_t orow2 = ((size_t)(2 * 8 + be) * NAa + na0 + lo) * CC;
  bfrag8 bf0[4], bf1[4], bf2[4];
#pragma unroll
  for (int kk = 0; kk < 4; kk++) {
    bf0[kk] = *(const bfrag8*)&o_part[orow0 + kk * 32 + g * 8];
    bf1[kk] = *(const bfrag8*)&o_part[orow1 + kk * 32 + g * 8];
    bf2[kk] = *(const bfrag8*)&o_part[orow2 + kk * 32 + g * 8];
  }
#pragma unroll
  for (int mt2 = 0; mt2 < 2; mt2++) {
    const int rowbase = (w * 2 + mt2) * 16;
    ffrag4 d = {0.f, 0.f, 0.f, 0.f};
#pragma unroll
    for (int kk = 0; kk < 4; kk++) {
      bfrag8 af = *(const bfrag8*)&wob[(size_t)(rowbase + lo) * CC + kk * 32 + g * 8];
      d = __builtin_amdgcn_mfma_f32_16x16x32_bf16(af, bf0[kk], d, 0, 0, 0);
      d = __builtin_amdgcn_mfma_f32_16x16x32_bf16(af, bf1[kk], d, 0, 0, 0);
      d = __builtin_amdgcn_mfma_f32_16x16x32_bf16(af, bf2[kk], d, 0, 0, 0);
    }
    const int ch0 = rowbase + 4 * g;
    const uint2 q0 = *(const uint2*)&o_part[orow0 + ch0];
    const uint2 q1 = *(const uint2*)&o_part[orow1 + ch0];
    const uint2 q2 = *(const uint2*)&o_part[orow2 + ch0];
    float ov[4] = {bfl(q0.x) + bfl(q1.x) + bfl(q2.x), bfh(q0.x) + bfh(q1.x) + bfh(q2.x),
                   bfl(q0.y) + bfl(q1.y) + bfl(q2.y), bfh(q0.y) + bfh(q1.y) + bfh(q2.y)};
#pragma unroll
    for (int r = 0; r < 4; r++) {
      const size_t xi = ((size_t)b * CC + ch0 + r) * NN + ng0 + lo;
      float y = d[r] + t_out[ch0 + r];
      out[xi] = ov[r] * sigmoid_fast(y) + x[xi];
    }
  }
}

extern "C" void kernel_launch(void* const* d_in, const int* in_sizes, int n_in,
                              void* d_out, int out_size, void* d_ws, size_t ws_size,
                              hipStream_t stream) {
  const float* x    = (const float*)d_in[0];
  const float* w_qk = (const float*)d_in[1];
  const float* s_qk = (const float*)d_in[2];
  const float* t_qk = (const float*)d_in[3];
  const float* w_in = (const float*)d_in[4];
  const float* s_in = (const float*)d_in[5];
  const float* t_in = (const float*)d_in[6];
  const float* w_out = (const float*)d_in[7];
  const float* s_out = (const float*)d_in[8];
  const float* t_out = (const float*)d_in[9];
  const float* w_fg = (const float*)d_in[10];
  const float* s_fg = (const float*)d_in[11];
  const float* t_fg = (const float*)d_in[12];

  char* wsb = (char*)d_ws;
  unsigned short* o_part = (unsigned short*)wsb;               // 9,830,400 B  [3 split][be][n][c] bf16
  unsigned short* vb_raw = (unsigned short*)(wsb + 9830400);   // 3,276,864 B
  unsigned short* vbp = vb_raw + 2;
  unsigned short* qt = (unsigned short*)(wsb + 13107264);      // 3,276,800 B
  unsigned short* kt = (unsigned short*)(wsb + 16384064);      // 3,276,800 B
  unsigned short* wqkb = (unsigned short*)(wsb + 19660864);    //    98,304 B
  unsigned short* wob = (unsigned short*)(wsb + 19759168);     //    32,768 B
  float* pstats = (float*)(wsb + 19791936);                    // 1,638,400 B -> total 21,430,336 B
  float* out = (float*)d_out;

  prep_kernel<<<10, 256, 0, stream>>>(w_qk, s_qk, w_in, s_in, w_out, s_out, wqkb, wob);
  qkv_kernel<<<800, 256, 0, stream>>>(x, wqkb, t_qk, t_in, qt, kt, vbp);
  stats_kernel<<<800, 256, 0, stream>>>(qt, kt, pstats);
  apply_kernel<<<2400, 256, 0, stream>>>(qt, kt, vbp, pstats, w_fg, s_fg, t_fg, o_part);
  out_kernel<<<800, 256, 0, stream>>>(o_part, wob, t_out, x, out);
}

// Round 9
// 128.364 us; speedup vs baseline: 1.0391x; 1.0391x over previous
//
#include <hip/hip_runtime.h>
#include <hip/hip_bf16.h>
#include <cstdint>

#define CC 128
#define NN 6400
#define NAa 1600
#define HEADS 4
#define HD 32
#define NB 32
#define MT 64

#define P_ROW 68
#define P_HEAD 1096   // 16*68+8 pad
#define A_ROW 76
#define A_HEAD 1224   // 16*76+8 pad
#define PW (HEADS * P_HEAD)   // 4384 elems per q-subtile
#define AW (HEADS * A_HEAD)   // 4896 elems per q-subtile
// halo buffer: [parity][qs][h][lo][4] bf16
#define HB_IDX(par, qs, hh, lo) (((((par)*2 + (qs))*4 + (hh))*16 + (lo)) * 4)
#define XROW 136              // qkv LDS x-tile row stride (16B-aligned: 272 B)

typedef __attribute__((ext_vector_type(8))) short bfrag8;
typedef __attribute__((ext_vector_type(4))) float ffrag4;
typedef union { uint2 u2[2]; bfrag8 f8; } cvt16;

#define LOG2E 1.4426950408889634f
#define QSCL (0.17677669529663687f * 1.4426950408889634f)

__device__ __forceinline__ float sigmoid_fast(float y) {
  return __builtin_amdgcn_rcpf(1.0f + __builtin_amdgcn_exp2f(-LOG2E * y));
}
__device__ __forceinline__ unsigned short f2bf(float f) {
  unsigned u = __float_as_uint(f);
  return (unsigned short)((u + 0x7FFFu + ((u >> 16) & 1u)) >> 16);
}
// packed 2xf32 -> 2xbf16 (RNE) — should emit v_cvt_pk_bf16_f32
__device__ __forceinline__ unsigned pk2(float a, float b) {
  float2 f2; f2.x = a; f2.y = b;
  __hip_bfloat162 h = __float22bfloat162_rn(f2);
  union { __hip_bfloat162 h2; unsigned u; } cv; cv.h2 = h;
  return cv.u;
}
__device__ __forceinline__ float bfl(unsigned u) { return __uint_as_float(u << 16); }
__device__ __forceinline__ float bfh(unsigned u) { return __uint_as_float(u & 0xFFFF0000u); }

// ---- K0: prep — weights->bf16 with scales folded (x-transpose fused into qkv) ----
__global__ __launch_bounds__(256) void prep_kernel(
    const float* __restrict__ w_qk, const float* __restrict__ s_qk,
    const float* __restrict__ w_in, const float* __restrict__ s_in,
    const float* __restrict__ w_out, const float* __restrict__ s_out,
    unsigned short* __restrict__ wqkb, unsigned short* __restrict__ wob) {
  const int blk = blockIdx.x, tid = threadIdx.x;
  if (blk < 8) {
    const int r0 = blk * 48;
    for (int i = tid; i < 6144; i += 256) {
      int r = r0 + (i >> 7), c = i & 127;
      float wv, sv;
      if (r < 2 * CC) { wv = w_qk[r * CC + c]; sv = s_qk[r] * (r < CC ? QSCL : 1.0f); }
      else           { wv = w_in[(r - 2 * CC) * CC + c]; sv = s_in[r - 2 * CC]; }
      wqkb[r * CC + c] = f2bf(wv * sv);
    }
  } else {
    const int r0 = (blk - 8) * 64;
    for (int i = tid; i < 8192; i += 256) {
      int r = r0 + (i >> 7), c = i & 127;
      wob[r * CC + c] = f2bf(w_out[r * CC + c] * s_out[r]);
    }
  }
}

// ---- K1: qkv as MFMA GEMM (384 x 6400 x K=128), x transposed in-block via LDS ----
__global__ __launch_bounds__(256) void qkv_kernel(
    const float* __restrict__ x, const unsigned short* __restrict__ wqkb,
    const float* __restrict__ t_qk, const float* __restrict__ t_in,
    unsigned short* __restrict__ qt, unsigned short* __restrict__ kt,
    unsigned short* __restrict__ vb) {
  __shared__ __align__(16) unsigned short xb[16 * XROW];  // 4352 B
  const int tid = threadIdx.x;
  const int w = tid >> 6, lane = tid & 63, lo = lane & 15, g = lane >> 4;
  const int blk = blockIdx.x;
  const int b = blk / 400, pt = blk - b * 400;
  const int ng0 = pt * 16;
  const int a = ng0 / NAa, na0 = ng0 - a * NAa;
  const int be = b * 4 + a;
  // ---- stage: transpose x[b][c][ng0..ng0+15] f32 -> xb[n][c] bf16 ----
  {
    const int c = tid >> 1, half = tid & 1;
    const float* xr = &x[((size_t)(b * CC + c)) * NN + ng0 + 8 * half];
    const float4 f0 = *(const float4*)xr;
    const float4 f1 = *(const float4*)(xr + 4);
    unsigned short* dst = &xb[(8 * half) * XROW + c];
    dst[0 * XROW] = f2bf(f0.x); dst[1 * XROW] = f2bf(f0.y);
    dst[2 * XROW] = f2bf(f0.z); dst[3 * XROW] = f2bf(f0.w);
    dst[4 * XROW] = f2bf(f1.x); dst[5 * XROW] = f2bf(f1.y);
    dst[6 * XROW] = f2bf(f1.z); dst[7 * XROW] = f2bf(f1.w);
  }
  __syncthreads();
  bfrag8 bf[4];
#pragma unroll
  for (int kk = 0; kk < 4; kk++) bf[kk] = *(const bfrag8*)&xb[lo * XROW + kk * 32 + g * 8];
#pragma unroll
  for (int mt6 = 0; mt6 < 6; mt6++) {
    const int rowbase = (w * 6 + mt6) * 16;
    ffrag4 d = {0.f, 0.f, 0.f, 0.f};
#pragma unroll
    for (int kk = 0; kk < 4; kk++) {
      bfrag8 af = *(const bfrag8*)&wqkb[(size_t)(rowbase + lo) * CC + kk * 32 + g * 8];
      d = __builtin_amdgcn_mfma_f32_16x16x32_bf16(af, bf[kk], d, 0, 0, 0);
    }
    const int r0c = rowbase + 4 * g;
    if (r0c < CC) {
      const int h = r0c >> 5, d0 = r0c & 31;
      uint2 pk;
      pk.x = pk2(d[0] + t_qk[r0c] * QSCL, d[1] + t_qk[r0c + 1] * QSCL);
      pk.y = pk2(d[2] + t_qk[r0c + 2] * QSCL, d[3] + t_qk[r0c + 3] * QSCL);
      *(uint2*)&qt[((size_t)(be * HEADS + h) * NAa + na0 + lo) * HD + d0] = pk;
    } else if (r0c < 2 * CC) {
      const int ch = r0c - CC, h = ch >> 5, d0 = ch & 31;
      uint2 pk;
      pk.x = pk2(d[0] + t_qk[r0c], d[1] + t_qk[r0c + 1]);
      pk.y = pk2(d[2] + t_qk[r0c + 2], d[3] + t_qk[r0c + 3]);
      *(uint2*)&kt[((size_t)(be * HEADS + h) * NAa + na0 + lo) * HD + d0] = pk;
    } else {
      const int ch0 = r0c - 2 * CC;
      const uint2 xv = *(const uint2*)&xb[lo * XROW + ch0];
      float xr[4] = {bfl(xv.x), bfh(xv.x), bfl(xv.y), bfh(xv.y)};
#pragma unroll
      for (int r = 0; r < 4; r++) {
        float y = d[r] + t_in[ch0 + r];
        vb[((size_t)be * CC + ch0 + r) * NAa + na0 + lo] = f2bf(sigmoid_fast(y) * xr[r]);
      }
    }
  }
}

// ---- K2a: partial softmax denominators (M0 = 0, q pre-scaled), 32 q/block ----
__global__ __launch_bounds__(256) void stats_kernel(
    const unsigned short* __restrict__ qt, const unsigned short* __restrict__ kt,
    float* __restrict__ pstats) {
  int tid = threadIdx.x;
  int h = tid >> 6, lane = tid & 63, lo = lane & 15, g = lane >> 4;
  int bid = blockIdx.x;
  int be = bid & 7;
  int rest = bid >> 3;
  int n0 = (rest % 50) * 32;
  int split = rest / 50;
  int ts0 = split ? 12 : 0, ts1 = split ? 25 : 12;

  const unsigned short* qtb = qt + (size_t)(be * HEADS + h) * NAa * HD;
  const unsigned short* ktb = kt + (size_t)(be * HEADS + h) * NAa * HD;

  bfrag8 qf0 = *(const bfrag8*)(qtb + (size_t)(n0 + lo) * HD + g * 8);
  bfrag8 qf1 = *(const bfrag8*)(qtb + (size_t)(n0 + 16 + lo) * HD + g * 8);
  float sm0[4] = {0.f, 0.f, 0.f, 0.f};
  float sm1[4] = {0.f, 0.f, 0.f, 0.f};
  for (int t = ts0; t < ts1; t++) {
    int m0 = t * MT;
#pragma unroll
    for (int sb = 0; sb < 4; sb++) {
      bfrag8 kf = *(const bfrag8*)(ktb + (size_t)(m0 + sb * 16 + lo) * HD + g * 8);
      ffrag4 z = {0.f, 0.f, 0.f, 0.f};
      ffrag4 c0 = __builtin_amdgcn_mfma_f32_16x16x32_bf16(qf0, kf, z, 0, 0, 0);
      ffrag4 c1 = __builtin_amdgcn_mfma_f32_16x16x32_bf16(qf1, kf, z, 0, 0, 0);
#pragma unroll
      for (int r = 0; r < 4; r++) {
        sm0[r] += __builtin_amdgcn_exp2f(c0[r]);
        sm1[r] += __builtin_amdgcn_exp2f(c1[r]);
      }
    }
  }
#pragma unroll
  for (int r = 0; r < 4; r++) {
#pragma unroll
    for (int off = 1; off <= 8; off <<= 1) {
      sm0[r] += __shfl_xor(sm0[r], off);
      sm1[r] += __shfl_xor(sm1[r], off);
    }
  }
  if (lo == 0) {
    float4 s4; s4.x = sm0[0]; s4.y = sm0[1]; s4.z = sm0[2]; s4.w = sm0[3];
    *(float4*)&pstats[((size_t)(split * 8 + be) * HEADS + h) * NAa + n0 + 4 * g] = s4;
    float4 s5; s5.x = sm1[0]; s5.y = sm1[1]; s5.z = sm1[2]; s5.w = sm1[3];
    *(float4*)&pstats[((size_t)(split * 8 + be) * HEADS + h) * NAa + n0 + 16 + 4 * g] = s5;
  }
}

// ---- K2b: apply — R7 structure (512 thr, NB=32, single-buffered P + parity
//      halo Hb) with 4-WAY key split (tiles 7/6/6/7, grid 1600): pushes average
//      residency toward the 4-block/CU LDS cap with richer phase stagger.
//      R8 lesson: do NOT shrink blocks — KV-fragment reuse per wave (2 qs share
//      every kf/vf) is the efficiency driver. No setprio (R6: regressed). ----
__global__ __launch_bounds__(512) void apply_kernel(
    const unsigned short* __restrict__ qt, const unsigned short* __restrict__ kt,
    const unsigned short* __restrict__ vb, const float* __restrict__ pstats,
    const float* __restrict__ w_fg, const float* __restrict__ s_fg,
    const float* __restrict__ t_fg, unsigned short* __restrict__ o_part) {
  __shared__ __align__(16) unsigned short Ps[2 * PW];   // 17536 B
  __shared__ __align__(16) unsigned short A2s[2 * AW];  // 19584 B
  __shared__ __align__(16) unsigned short Hb[1024];     //  2048 B halo [par][qs][h][lo][4]
  const int tid = threadIdx.x;
  const int w = tid >> 6, lane = tid & 63, lo = lane & 15, g = lane >> 4;
  const int h = w >> 1, u = w & 1;
  const int bid = blockIdx.x;
  const int be = bid & 7;
  const int rest = bid >> 3;
  const int n0 = (rest % 50) * NB;
  const int split = rest / 50;                         // 0..3
  const int ts0 = (split == 0) ? 0 : (split == 1 ? 7 : (split == 2 ? 13 : 19));
  const int tend = (split == 0) ? 7 : (split == 1 ? 13 : (split == 2 ? 19 : 26));
  const int p0 = ts0 & 1;

  const unsigned short* qtb = qt + (size_t)(be * HEADS + h) * NAa * HD;
  const unsigned short* ktb = kt + (size_t)(be * HEADS + h) * NAa * HD;
  const unsigned short* vhb = vb + (size_t)(be * CC + h * HD) * NAa;

  bfrag8 qf[2];
#pragma unroll
  for (int qs = 0; qs < 2; ++qs)
    qf[qs] = *(const bfrag8*)(qtb + (size_t)(n0 + 16 * qs + lo) * HD + g * 8);

  // conv-weight A-fragment (constant): row=lo=(ho*4+s), k=g*8+j
  bfrag8 wfrag;
  {
    const int ho = lo >> 2, s = lo & 3;
#pragma unroll
    for (int j = 0; j < 8; j++) {
      const int tp = j - s;
      float wv = (tp >= 0 && tp < 5) ? w_fg[(ho * HEADS + g) * 5 + tp] : 0.0f;
      wfrag[j] = (short)f2bf(wv);
    }
  }
  const float sfv = s_fg[g], tfv = t_fg[g];

  // -log2(denominator) per q-subtile, folded into QK's MFMA accumulator
  float linv[2];
#pragma unroll
  for (int qs = 0; qs < 2; ++qs) {
    const float den = pstats[((size_t)(0 + be) * HEADS + h) * NAa + n0 + 16 * qs + lo] +
                      pstats[((size_t)(8 + be) * HEADS + h) * NAa + n0 + 16 * qs + lo];
    linv[qs] = -__log2f(den);
  }

  ffrag4 oacc[2][2];
#pragma unroll
  for (int qs = 0; qs < 2; ++qs) {
    ffrag4 z = {0.f, 0.f, 0.f, 0.f};
    oacc[qs][0] = z; oacc[qs][1] = z;
  }

  // ---- prologue: Hb[p0] = halo for conv(ts0) ----
  if (split == 0) {
    if (u == 0 && g == 0) {
      uint2 zz; zz.x = 0; zz.y = 0;
#pragma unroll
      for (int qs = 0; qs < 2; ++qs)
        *(uint2*)&Hb[HB_IDX(p0, qs, h, lo)] = zz;
    }
  } else if (u == 0) {
    // halo keys ts0*64-4..-1 from K rows ts0*64-16..-1 (g==3 lanes hold them)
    bfrag8 kf = *(const bfrag8*)(ktb + (size_t)(ts0 * MT - 16 + lo) * HD + g * 8);
#pragma unroll
    for (int qs = 0; qs < 2; ++qs) {
      ffrag4 cin = {linv[qs], linv[qs], linv[qs], linv[qs]};
      ffrag4 c = __builtin_amdgcn_mfma_f32_16x16x32_bf16(kf, qf[qs], cin, 0, 0, 0);
      if (g == 3) {
        uint2 pk;
        pk.x = pk2(__builtin_amdgcn_exp2f(c[0]), __builtin_amdgcn_exp2f(c[1]));
        pk.y = pk2(__builtin_amdgcn_exp2f(c[2]), __builtin_amdgcn_exp2f(c[3]));
        *(uint2*)&Hb[HB_IDX(p0, qs, h, lo)] = pk;
      }
    }
  }
  // ---- prologue: QK(ts0) -> Ps; sb==3/g==3 lanes also feed Hb[p0^1] ----
  {
    const int m0 = ts0 * MT;
#pragma unroll
    for (int sbi = 0; sbi < 2; sbi++) {
      const int sb = 2 * u + sbi;
      bfrag8 kf = *(const bfrag8*)(ktb + (size_t)(m0 + sb * 16 + lo) * HD + g * 8);
#pragma unroll
      for (int qs = 0; qs < 2; ++qs) {
        ffrag4 cin = {linv[qs], linv[qs], linv[qs], linv[qs]};
        ffrag4 c = __builtin_amdgcn_mfma_f32_16x16x32_bf16(kf, qf[qs], cin, 0, 0, 0);
        uint2 pk;
        pk.x = pk2(__builtin_amdgcn_exp2f(c[0]), __builtin_amdgcn_exp2f(c[1]));
        pk.y = pk2(__builtin_amdgcn_exp2f(c[2]), __builtin_amdgcn_exp2f(c[3]));
        *(uint2*)&Ps[qs * PW + h * P_HEAD + lo * P_ROW + 16 * sb + 4 * g] = pk;
        if (sb == 3 && g == 3)
          *(uint2*)&Hb[HB_IDX(p0 ^ 1, qs, h, lo)] = pk;
      }
    }
  }
  __syncthreads();

  for (int t = ts0; t < tend; t++) {
    const int m0 = t * MT;
    const int par = t & 1;
    // early V loads (k-half u) for PV(t) — shared across q-subtiles
    const bfrag8 vf0 = *(const bfrag8*)(vhb + (size_t)lo * NAa + (m0 - 2 + 32 * u + 8 * g));
    const bfrag8 vf1 = *(const bfrag8*)(vhb + (size_t)(16 + lo) * NAa + (m0 - 2 + 32 * u + 8 * g));
    const bool doqk = (t + 1 < tend);
    const bool realqk = doqk && (t + 1 < 25);
    bfrag8 kf0, kf1;
    if (realqk) {
      const int m1 = (t + 1) * MT;
      kf0 = *(const bfrag8*)(ktb + (size_t)(m1 + (2 * u) * 16 + lo) * HD + g * 8);
      kf1 = *(const bfrag8*)(ktb + (size_t)(m1 + (2 * u + 1) * 16 + lo) * HD + g * 8);
    }
    // ---- phase 1: conv(t) reads Ps/Hb -> writes A2s ----
    const bool edge = (t == 0) || (t == 25);
#pragma unroll
    for (int qs = 0; qs < 2; ++qs) {
#pragma unroll
      for (int ii = 0; ii < 2; ii++) {
        const int i = 2 * w + ii;
        cvt16 bb;
        if (i == 0)
          bb.u2[0] = *(const uint2*)&Hb[HB_IDX(par, qs, g, lo)];
        else
          bb.u2[0] = *(const uint2*)&Ps[qs * PW + g * P_HEAD + lo * P_ROW + 4 * i - 4];
        bb.u2[1] = *(const uint2*)&Ps[qs * PW + g * P_HEAD + lo * P_ROW + 4 * i];
        ffrag4 z = {0.f, 0.f, 0.f, 0.f};
        ffrag4 d = __builtin_amdgcn_mfma_f32_16x16x32_bf16(wfrag, bb.f8, z, 0, 0, 0);
        float a2v[4];
        if (edge) {
#pragma unroll
          for (int r = 0; r < 4; r++) {
            const int mp = m0 - 2 + 4 * i + r;
            float y = d[r] * sfv + tfv;
            float v = y * sigmoid_fast(y);
            a2v[r] = (mp >= 0 && mp < NAa) ? v : 0.0f;
          }
        } else {
#pragma unroll
          for (int r = 0; r < 4; r++) {
            float y = d[r] * sfv + tfv;
            a2v[r] = y * sigmoid_fast(y);
          }
        }
        uint2 pk;
        pk.x = pk2(a2v[0], a2v[1]);
        pk.y = pk2(a2v[2], a2v[3]);
        *(uint2*)&A2s[qs * AW + g * A_HEAD + lo * A_ROW + 4 * i] = pk;
      }
    }
    __syncthreads();
    // ---- phase 2: QK(t+1) -> Ps/Hb, then PV(t) reads A2s ----
    if (doqk) {
      if (realqk) {
#pragma unroll
        for (int qs = 0; qs < 2; ++qs) {
          ffrag4 cin = {linv[qs], linv[qs], linv[qs], linv[qs]};
          ffrag4 c0 = __builtin_amdgcn_mfma_f32_16x16x32_bf16(kf0, qf[qs], cin, 0, 0, 0);
          ffrag4 c1 = __builtin_amdgcn_mfma_f32_16x16x32_bf16(kf1, qf[qs], cin, 0, 0, 0);
          uint2 pk;
          pk.x = pk2(__builtin_amdgcn_exp2f(c0[0]), __builtin_amdgcn_exp2f(c0[1]));
          pk.y = pk2(__builtin_amdgcn_exp2f(c0[2]), __builtin_amdgcn_exp2f(c0[3]));
          *(uint2*)&Ps[qs * PW + h * P_HEAD + lo * P_ROW + 16 * (2 * u) + 4 * g] = pk;
          uint2 pk1;
          pk1.x = pk2(__builtin_amdgcn_exp2f(c1[0]), __builtin_amdgcn_exp2f(c1[1]));
          pk1.y = pk2(__builtin_amdgcn_exp2f(c1[2]), __builtin_amdgcn_exp2f(c1[3]));
          *(uint2*)&Ps[qs * PW + h * P_HEAD + lo * P_ROW + 16 * (2 * u + 1) + 4 * g] = pk1;
          if (u == 1 && g == 3)
            *(uint2*)&Hb[HB_IDX(par, qs, h, lo)] = pk1;   // halo for conv(t+2)
        }
      } else {
        uint2 zz; zz.x = 0; zz.y = 0;
#pragma unroll
        for (int qs = 0; qs < 2; ++qs) {
          *(uint2*)&Ps[qs * PW + h * P_HEAD + lo * P_ROW + 16 * (2 * u) + 4 * g] = zz;
          *(uint2*)&Ps[qs * PW + h * P_HEAD + lo * P_ROW + 16 * (2 * u + 1) + 4 * g] = zz;
        }
      }
    }
    // PV(t): head h, k-half u, both qsubs (V frags shared)
#pragma unroll
    for (int qs = 0; qs < 2; ++qs) {
      cvt16 av;
      av.u2[0] = *(const uint2*)&A2s[qs * AW + h * A_HEAD + lo * A_ROW + 32 * u + 8 * g];
      av.u2[1] = *(const uint2*)&A2s[qs * AW + h * A_HEAD + lo * A_ROW + 32 * u + 8 * g + 4];
      oacc[qs][0] = __builtin_amdgcn_mfma_f32_16x16x32_bf16(av.f8, vf0, oacc[qs][0], 0, 0, 0);
      oacc[qs][1] = __builtin_amdgcn_mfma_f32_16x16x32_bf16(av.f8, vf1, oacc[qs][1], 0, 0, 0);
    }
    __syncthreads();
  }

  // ---- cross-u reduction via A2s scratch, write o_part [split][be][n][c] bf16 ----
  float* scr = (float*)A2s;
  if (u == 1) {
#pragma unroll
    for (int qs = 0; qs < 2; ++qs) {
      float4 f0; f0.x = oacc[qs][0][0]; f0.y = oacc[qs][0][1]; f0.z = oacc[qs][0][2]; f0.w = oacc[qs][0][3];
      float4 f1; f1.x = oacc[qs][1][0]; f1.y = oacc[qs][1][1]; f1.z = oacc[qs][1][2]; f1.w = oacc[qs][1][3];
      *(float4*)&scr[((qs * 4 + h) * 64 + lane) * 8] = f0;
      *(float4*)&scr[((qs * 4 + h) * 64 + lane) * 8 + 4] = f1;
    }
  }
  __syncthreads();
  if (u == 0) {
#pragma unroll
    for (int qs = 0; qs < 2; ++qs) {
      const float4 f0 = *(const float4*)&scr[((qs * 4 + h) * 64 + lane) * 8];
      const float4 f1 = *(const float4*)&scr[((qs * 4 + h) * 64 + lane) * 8 + 4];
      const float fa[4] = {f0.x, f0.y, f0.z, f0.w};
      const float fb[4] = {f1.x, f1.y, f1.z, f1.w};
#pragma unroll
      for (int r = 0; r < 4; r++) {
        const size_t rowoff = ((size_t)(split * 8 + be) * NAa + n0 + 16 * qs + 4 * g + r) * CC;
        o_part[rowoff + h * HD + lo] = f2bf(oacc[qs][0][r] + fa[r]);
        o_part[rowoff + h * HD + 16 + lo] = f2bf(oacc[qs][1][r] + fb[r]);
      }
    }
  }
}

// ---- K3: out as MFMA GEMM + SiLU-gate + residual (sums 4 o_part splits) ----
__global__ __launch_bounds__(256) void out_kernel(
    const unsigned short* __restrict__ o_part, const unsigned short* __restrict__ wob,
    const float* __restrict__ t_out, const float* __restrict__ x,
    float* __restrict__ out) {
  const int tid = threadIdx.x;
  const int w = tid >> 6, lane = tid & 63, lo = lane & 15, g = lane >> 4;
  const int blk = blockIdx.x;
  const int b = blk / 400, pt = blk - b * 400;
  const int ng0 = pt * 16;
  const int a = ng0 / NAa, na0 = ng0 - a * NAa;
  const int be = b * 4 + a;
  size_t orow[4];
#pragma unroll
  for (int s = 0; s < 4; s++)
    orow[s] = ((size_t)(s * 8 + be) * NAa + na0 + lo) * CC;
  bfrag8 bfs[4][4];
#pragma unroll
  for (int s = 0; s < 4; s++)
#pragma unroll
    for (int kk = 0; kk < 4; kk++)
      bfs[s][kk] = *(const bfrag8*)&o_part[orow[s] + kk * 32 + g * 8];
#pragma unroll
  for (int mt2 = 0; mt2 < 2; mt2++) {
    const int rowbase = (w * 2 + mt2) * 16;
    ffrag4 d = {0.f, 0.f, 0.f, 0.f};
#pragma unroll
    for (int kk = 0; kk < 4; kk++) {
      bfrag8 af = *(const bfrag8*)&wob[(size_t)(rowbase + lo) * CC + kk * 32 + g * 8];
#pragma unroll
      for (int s = 0; s < 4; s++)
        d = __builtin_amdgcn_mfma_f32_16x16x32_bf16(af, bfs[s][kk], d, 0, 0, 0);
    }
    const int ch0 = rowbase + 4 * g;
    float ov[4] = {0.f, 0.f, 0.f, 0.f};
#pragma unroll
    for (int s = 0; s < 4; s++) {
      const uint2 q = *(const uint2*)&o_part[orow[s] + ch0];
      ov[0] += bfl(q.x); ov[1] += bfh(q.x);
      ov[2] += bfl(q.y); ov[3] += bfh(q.y);
    }
#pragma unroll
    for (int r = 0; r < 4; r++) {
      const size_t xi = ((size_t)b * CC + ch0 + r) * NN + ng0 + lo;
      float y = d[r] + t_out[ch0 + r];
      out[xi] = ov[r] * sigmoid_fast(y) + x[xi];
    }
  }
}

extern "C" void kernel_launch(void* const* d_in, const int* in_sizes, int n_in,
                              void* d_out, int out_size, void* d_ws, size_t ws_size,
                              hipStream_t stream) {
  const float* x    = (const float*)d_in[0];
  const float* w_qk = (const float*)d_in[1];
  const float* s_qk = (const float*)d_in[2];
  const float* t_qk = (const float*)d_in[3];
  const float* w_in = (const float*)d_in[4];
  const float* s_in = (const float*)d_in[5];
  const float* t_in = (const float*)d_in[6];
  const float* w_out = (const float*)d_in[7];
  const float* s_out = (const float*)d_in[8];
  const float* t_out = (const float*)d_in[9];
  const float* w_fg = (const float*)d_in[10];
  const float* s_fg = (const float*)d_in[11];
  const float* t_fg = (const float*)d_in[12];

  char* wsb = (char*)d_ws;
  unsigned short* o_part = (unsigned short*)wsb;                // 13,107,200 B [4 split][be][n][c] bf16
  unsigned short* vb_raw = (unsigned short*)(wsb + 13107200);   //  3,276,864 B
  unsigned short* vbp = vb_raw + 2;
  unsigned short* qt = (unsigned short*)(wsb + 16384064);       //  3,276,800 B
  unsigned short* kt = (unsigned short*)(wsb + 19660864);       //  3,276,800 B
  unsigned short* wqkb = (unsigned short*)(wsb + 22937664);     //     98,304 B
  unsigned short* wob = (unsigned short*)(wsb + 23035968);      //     32,768 B
  float* pstats = (float*)(wsb + 23068736);                     //  1,638,400 B -> total 24,707,136 B
  float* out = (float*)d_out;

  prep_kernel<<<10, 256, 0, stream>>>(w_qk, s_qk, w_in, s_in, w_out, s_out, wqkb, wob);
  qkv_kernel<<<800, 256, 0, stream>>>(x, wqkb, t_qk, t_in, qt, kt, vbp);
  stats_kernel<<<800, 256, 0, stream>>>(qt, kt, pstats);
  apply_kernel<<<1600, 512, 0, stream>>>(qt, kt, vbp, pstats, w_fg, s_fg, t_fg, o_part);
  out_kernel<<<800, 256, 0, stream>>>(o_part, wob, t_out, x, out);
}

// Round 10
// 118.797 us; speedup vs baseline: 1.1228x; 1.0805x over previous
//
#include <hip/hip_runtime.h>
#include <hip/hip_bf16.h>
#include <cstdint>

#define CC 128
#define NN 6400
#define NAa 1600
#define HEADS 4
#define HD 32
#define NB 32
#define MT 64

#define P_ROW 68
#define P_HEAD 1096   // 16*68+8 pad
#define A_ROW 76
#define A_HEAD 1224   // 16*76+8 pad
#define PW (HEADS * P_HEAD)   // 4384 elems per q-subtile
#define AW (HEADS * A_HEAD)   // 4896 elems per q-subtile
// halo buffer: [parity][qs][h][lo][4] bf16
#define HB_IDX(par, qs, hh, lo) (((((par)*2 + (qs))*4 + (hh))*16 + (lo)) * 4)
#define XROW 136              // qkv LDS x-tile row stride (16B-aligned: 272 B)

typedef __attribute__((ext_vector_type(8))) short bfrag8;
typedef __attribute__((ext_vector_type(4))) float ffrag4;
typedef union { uint2 u2[2]; bfrag8 f8; } cvt16;

#define LOG2E 1.4426950408889634f
#define QSCL (0.17677669529663687f * 1.4426950408889634f)

__device__ __forceinline__ float sigmoid_fast(float y) {
  return __builtin_amdgcn_rcpf(1.0f + __builtin_amdgcn_exp2f(-LOG2E * y));
}
__device__ __forceinline__ unsigned short f2bf(float f) {
  unsigned u = __float_as_uint(f);
  return (unsigned short)((u + 0x7FFFu + ((u >> 16) & 1u)) >> 16);
}
// packed 2xf32 -> 2xbf16 (RNE) — should emit v_cvt_pk_bf16_f32
__device__ __forceinline__ unsigned pk2(float a, float b) {
  float2 f2; f2.x = a; f2.y = b;
  __hip_bfloat162 h = __float22bfloat162_rn(f2);
  union { __hip_bfloat162 h2; unsigned u; } cv; cv.h2 = h;
  return cv.u;
}
__device__ __forceinline__ float bfl(unsigned u) { return __uint_as_float(u << 16); }
__device__ __forceinline__ float bfh(unsigned u) { return __uint_as_float(u & 0xFFFF0000u); }

// ---- K0: prep — weights->bf16 with scales folded (x-transpose fused into qkv) ----
__global__ __launch_bounds__(256) void prep_kernel(
    const float* __restrict__ w_qk, const float* __restrict__ s_qk,
    const float* __restrict__ w_in, const float* __restrict__ s_in,
    const float* __restrict__ w_out, const float* __restrict__ s_out,
    unsigned short* __restrict__ wqkb, unsigned short* __restrict__ wob) {
  const int blk = blockIdx.x, tid = threadIdx.x;
  if (blk < 8) {
    const int r0 = blk * 48;
    for (int i = tid; i < 6144; i += 256) {
      int r = r0 + (i >> 7), c = i & 127;
      float wv, sv;
      if (r < 2 * CC) { wv = w_qk[r * CC + c]; sv = s_qk[r] * (r < CC ? QSCL : 1.0f); }
      else           { wv = w_in[(r - 2 * CC) * CC + c]; sv = s_in[r - 2 * CC]; }
      wqkb[r * CC + c] = f2bf(wv * sv);
    }
  } else {
    const int r0 = (blk - 8) * 64;
    for (int i = tid; i < 8192; i += 256) {
      int r = r0 + (i >> 7), c = i & 127;
      wob[r * CC + c] = f2bf(w_out[r * CC + c] * s_out[r]);
    }
  }
}

// ---- K1: qkv as MFMA GEMM (384 x 6400 x K=128), x transposed in-block via LDS ----
__global__ __launch_bounds__(256) void qkv_kernel(
    const float* __restrict__ x, const unsigned short* __restrict__ wqkb,
    const float* __restrict__ t_qk, const float* __restrict__ t_in,
    unsigned short* __restrict__ qt, unsigned short* __restrict__ kt,
    unsigned short* __restrict__ vb) {
  __shared__ __align__(16) unsigned short xb[16 * XROW];  // 4352 B
  const int tid = threadIdx.x;
  const int w = tid >> 6, lane = tid & 63, lo = lane & 15, g = lane >> 4;
  const int blk = blockIdx.x;
  const int b = blk / 400, pt = blk - b * 400;
  const int ng0 = pt * 16;
  const int a = ng0 / NAa, na0 = ng0 - a * NAa;
  const int be = b * 4 + a;
  // ---- stage: transpose x[b][c][ng0..ng0+15] f32 -> xb[n][c] bf16 ----
  {
    const int c = tid >> 1, half = tid & 1;
    const float* xr = &x[((size_t)(b * CC + c)) * NN + ng0 + 8 * half];
    const float4 f0 = *(const float4*)xr;
    const float4 f1 = *(const float4*)(xr + 4);
    unsigned short* dst = &xb[(8 * half) * XROW + c];
    dst[0 * XROW] = f2bf(f0.x); dst[1 * XROW] = f2bf(f0.y);
    dst[2 * XROW] = f2bf(f0.z); dst[3 * XROW] = f2bf(f0.w);
    dst[4 * XROW] = f2bf(f1.x); dst[5 * XROW] = f2bf(f1.y);
    dst[6 * XROW] = f2bf(f1.z); dst[7 * XROW] = f2bf(f1.w);
  }
  __syncthreads();
  bfrag8 bf[4];
#pragma unroll
  for (int kk = 0; kk < 4; kk++) bf[kk] = *(const bfrag8*)&xb[lo * XROW + kk * 32 + g * 8];
#pragma unroll
  for (int mt6 = 0; mt6 < 6; mt6++) {
    const int rowbase = (w * 6 + mt6) * 16;
    ffrag4 d = {0.f, 0.f, 0.f, 0.f};
#pragma unroll
    for (int kk = 0; kk < 4; kk++) {
      bfrag8 af = *(const bfrag8*)&wqkb[(size_t)(rowbase + lo) * CC + kk * 32 + g * 8];
      d = __builtin_amdgcn_mfma_f32_16x16x32_bf16(af, bf[kk], d, 0, 0, 0);
    }
    const int r0c = rowbase + 4 * g;
    if (r0c < CC) {
      const int h = r0c >> 5, d0 = r0c & 31;
      uint2 pk;
      pk.x = pk2(d[0] + t_qk[r0c] * QSCL, d[1] + t_qk[r0c + 1] * QSCL);
      pk.y = pk2(d[2] + t_qk[r0c + 2] * QSCL, d[3] + t_qk[r0c + 3] * QSCL);
      *(uint2*)&qt[((size_t)(be * HEADS + h) * NAa + na0 + lo) * HD + d0] = pk;
    } else if (r0c < 2 * CC) {
      const int ch = r0c - CC, h = ch >> 5, d0 = ch & 31;
      uint2 pk;
      pk.x = pk2(d[0] + t_qk[r0c], d[1] + t_qk[r0c + 1]);
      pk.y = pk2(d[2] + t_qk[r0c + 2], d[3] + t_qk[r0c + 3]);
      *(uint2*)&kt[((size_t)(be * HEADS + h) * NAa + na0 + lo) * HD + d0] = pk;
    } else {
      const int ch0 = r0c - 2 * CC;
      const uint2 xv = *(const uint2*)&xb[lo * XROW + ch0];
      float xr[4] = {bfl(xv.x), bfh(xv.x), bfl(xv.y), bfh(xv.y)};
#pragma unroll
      for (int r = 0; r < 4; r++) {
        float y = d[r] + t_in[ch0 + r];
        vb[((size_t)be * CC + ch0 + r) * NAa + na0 + lo] = f2bf(sigmoid_fast(y) * xr[r]);
      }
    }
  }
}

// ---- K2a: partial softmax denominators (M0 = 0, q pre-scaled) ----
//      64 queries x 4 key-splits per block (grid stays 800 -> occupancy kept):
//      each kf B-fragment feeds FOUR MFMAs, halving K loads + addressing again.
__global__ __launch_bounds__(256) void stats_kernel(
    const unsigned short* __restrict__ qt, const unsigned short* __restrict__ kt,
    float* __restrict__ pstats) {
  int tid = threadIdx.x;
  int h = tid >> 6, lane = tid & 63, lo = lane & 15, g = lane >> 4;
  int bid = blockIdx.x;
  int be = bid & 7;
  int rest = bid >> 3;            // 0..99
  int n0 = (rest % 25) * 64;
  int ks = rest / 25;             // 0..3
  int ts0 = (ks == 0) ? 0 : (ks == 1 ? 7 : (ks == 2 ? 13 : 19));
  int ts1 = (ks == 0) ? 7 : (ks == 1 ? 13 : (ks == 2 ? 19 : 25));

  const unsigned short* qtb = qt + (size_t)(be * HEADS + h) * NAa * HD;
  const unsigned short* ktb = kt + (size_t)(be * HEADS + h) * NAa * HD;

  bfrag8 qf[4];
#pragma unroll
  for (int qq = 0; qq < 4; qq++)
    qf[qq] = *(const bfrag8*)(qtb + (size_t)(n0 + 16 * qq + lo) * HD + g * 8);
  float sm[4][4];
#pragma unroll
  for (int qq = 0; qq < 4; qq++)
#pragma unroll
    for (int r = 0; r < 4; r++) sm[qq][r] = 0.f;

  for (int t = ts0; t < ts1; t++) {
    int m0 = t * MT;
#pragma unroll
    for (int sb = 0; sb < 4; sb++) {
      bfrag8 kf = *(const bfrag8*)(ktb + (size_t)(m0 + sb * 16 + lo) * HD + g * 8);
#pragma unroll
      for (int qq = 0; qq < 4; qq++) {
        ffrag4 z = {0.f, 0.f, 0.f, 0.f};
        ffrag4 c = __builtin_amdgcn_mfma_f32_16x16x32_bf16(qf[qq], kf, z, 0, 0, 0);
#pragma unroll
        for (int r = 0; r < 4; r++) sm[qq][r] += __builtin_amdgcn_exp2f(c[r]);
      }
    }
  }
#pragma unroll
  for (int qq = 0; qq < 4; qq++)
#pragma unroll
    for (int r = 0; r < 4; r++) {
#pragma unroll
      for (int off = 1; off <= 8; off <<= 1) sm[qq][r] += __shfl_xor(sm[qq][r], off);
    }
  if (lo == 0) {
#pragma unroll
    for (int qq = 0; qq < 4; qq++) {
      float4 s4; s4.x = sm[qq][0]; s4.y = sm[qq][1]; s4.z = sm[qq][2]; s4.w = sm[qq][3];
      *(float4*)&pstats[((size_t)(ks * 8 + be) * HEADS + h) * NAa + n0 + 16 * qq + 4 * g] = s4;
    }
  }
}

// ---- K2b: apply — R7 structure (512 thr, NB=32, single-buffered P + parity
//      halo Hb, 3-WAY key split, grid 1200 — R9 proved 4-way regresses).
//      New: conv carries the overlapping uint2 (cell 2w+1 low half = cell 2w
//      high half) — 25% fewer conv LDS reads + addr VALU. No setprio (R6). ----
__global__ __launch_bounds__(512) void apply_kernel(
    const unsigned short* __restrict__ qt, const unsigned short* __restrict__ kt,
    const unsigned short* __restrict__ vb, const float* __restrict__ pstats,
    const float* __restrict__ w_fg, const float* __restrict__ s_fg,
    const float* __restrict__ t_fg, unsigned short* __restrict__ o_part) {
  __shared__ __align__(16) unsigned short Ps[2 * PW];   // 17536 B
  __shared__ __align__(16) unsigned short A2s[2 * AW];  // 19584 B
  __shared__ __align__(16) unsigned short Hb[1024];     //  2048 B halo [par][qs][h][lo][4]
  const int tid = threadIdx.x;
  const int w = tid >> 6, lane = tid & 63, lo = lane & 15, g = lane >> 4;
  const int h = w >> 1, u = w & 1;
  const int bid = blockIdx.x;
  const int be = bid & 7;
  const int rest = bid >> 3;
  const int n0 = (rest % 50) * NB;
  const int split = rest / 50;                         // 0..2
  const int ts0 = (split == 0) ? 0 : (split == 1 ? 9 : 17);
  const int tend = (split == 0) ? 9 : (split == 1 ? 17 : 26);  // t=25 virtual tail
  const int p0 = ts0 & 1;

  const unsigned short* qtb = qt + (size_t)(be * HEADS + h) * NAa * HD;
  const unsigned short* ktb = kt + (size_t)(be * HEADS + h) * NAa * HD;
  const unsigned short* vhb = vb + (size_t)(be * CC + h * HD) * NAa;

  bfrag8 qf[2];
#pragma unroll
  for (int qs = 0; qs < 2; ++qs)
    qf[qs] = *(const bfrag8*)(qtb + (size_t)(n0 + 16 * qs + lo) * HD + g * 8);

  // conv-weight A-fragment (constant): row=lo=(ho*4+s), k=g*8+j
  bfrag8 wfrag;
  {
    const int ho = lo >> 2, s = lo & 3;
#pragma unroll
    for (int j = 0; j < 8; j++) {
      const int tp = j - s;
      float wv = (tp >= 0 && tp < 5) ? w_fg[(ho * HEADS + g) * 5 + tp] : 0.0f;
      wfrag[j] = (short)f2bf(wv);
    }
  }
  const float sfv = s_fg[g], tfv = t_fg[g];

  // -log2(denominator) per q-subtile (4 key-split partials), folded into MFMA C-in
  float linv[2];
#pragma unroll
  for (int qs = 0; qs < 2; ++qs) {
    float den = 0.f;
#pragma unroll
    for (int ks = 0; ks < 4; ++ks)
      den += pstats[((size_t)(ks * 8 + be) * HEADS + h) * NAa + n0 + 16 * qs + lo];
    linv[qs] = -__log2f(den);
  }

  ffrag4 oacc[2][2];
#pragma unroll
  for (int qs = 0; qs < 2; ++qs) {
    ffrag4 z = {0.f, 0.f, 0.f, 0.f};
    oacc[qs][0] = z; oacc[qs][1] = z;
  }

  // ---- prologue: Hb[p0] = halo for conv(ts0) ----
  if (split == 0) {
    if (u == 0 && g == 0) {
      uint2 zz; zz.x = 0; zz.y = 0;
#pragma unroll
      for (int qs = 0; qs < 2; ++qs)
        *(uint2*)&Hb[HB_IDX(p0, qs, h, lo)] = zz;
    }
  } else if (u == 0) {
    // halo keys ts0*64-4..-1 from K rows ts0*64-16..-1 (g==3 lanes hold them)
    bfrag8 kf = *(const bfrag8*)(ktb + (size_t)(ts0 * MT - 16 + lo) * HD + g * 8);
#pragma unroll
    for (int qs = 0; qs < 2; ++qs) {
      ffrag4 cin = {linv[qs], linv[qs], linv[qs], linv[qs]};
      ffrag4 c = __builtin_amdgcn_mfma_f32_16x16x32_bf16(kf, qf[qs], cin, 0, 0, 0);
      if (g == 3) {
        uint2 pk;
        pk.x = pk2(__builtin_amdgcn_exp2f(c[0]), __builtin_amdgcn_exp2f(c[1]));
        pk.y = pk2(__builtin_amdgcn_exp2f(c[2]), __builtin_amdgcn_exp2f(c[3]));
        *(uint2*)&Hb[HB_IDX(p0, qs, h, lo)] = pk;
      }
    }
  }
  // ---- prologue: QK(ts0) -> Ps; sb==3/g==3 lanes also feed Hb[p0^1] ----
  {
    const int m0 = ts0 * MT;
#pragma unroll
    for (int sbi = 0; sbi < 2; sbi++) {
      const int sb = 2 * u + sbi;
      bfrag8 kf = *(const bfrag8*)(ktb + (size_t)(m0 + sb * 16 + lo) * HD + g * 8);
#pragma unroll
      for (int qs = 0; qs < 2; ++qs) {
        ffrag4 cin = {linv[qs], linv[qs], linv[qs], linv[qs]};
        ffrag4 c = __builtin_amdgcn_mfma_f32_16x16x32_bf16(kf, qf[qs], cin, 0, 0, 0);
        uint2 pk;
        pk.x = pk2(__builtin_amdgcn_exp2f(c[0]), __builtin_amdgcn_exp2f(c[1]));
        pk.y = pk2(__builtin_amdgcn_exp2f(c[2]), __builtin_amdgcn_exp2f(c[3]));
        *(uint2*)&Ps[qs * PW + h * P_HEAD + lo * P_ROW + 16 * sb + 4 * g] = pk;
        if (sb == 3 && g == 3)
          *(uint2*)&Hb[HB_IDX(p0 ^ 1, qs, h, lo)] = pk;
      }
    }
  }
  __syncthreads();

  for (int t = ts0; t < tend; t++) {
    const int m0 = t * MT;
    const int par = t & 1;
    // early V loads (k-half u) for PV(t) — shared across q-subtiles
    const bfrag8 vf0 = *(const bfrag8*)(vhb + (size_t)lo * NAa + (m0 - 2 + 32 * u + 8 * g));
    const bfrag8 vf1 = *(const bfrag8*)(vhb + (size_t)(16 + lo) * NAa + (m0 - 2 + 32 * u + 8 * g));
    const bool doqk = (t + 1 < tend);
    const bool realqk = doqk && (t + 1 < 25);
    bfrag8 kf0, kf1;
    if (realqk) {
      const int m1 = (t + 1) * MT;
      kf0 = *(const bfrag8*)(ktb + (size_t)(m1 + (2 * u) * 16 + lo) * HD + g * 8);
      kf1 = *(const bfrag8*)(ktb + (size_t)(m1 + (2 * u + 1) * 16 + lo) * HD + g * 8);
    }
    // ---- phase 1: conv(t) reads Ps/Hb -> writes A2s (carry overlapping uint2) ----
    const bool edge = (t == 0) || (t == 25);
#pragma unroll
    for (int qs = 0; qs < 2; ++qs) {
      uint2 carry;
#pragma unroll
      for (int ii = 0; ii < 2; ii++) {
        const int i = 2 * w + ii;
        cvt16 bb;
        if (ii == 0) {
          if (i == 0)
            bb.u2[0] = *(const uint2*)&Hb[HB_IDX(par, qs, g, lo)];
          else
            bb.u2[0] = *(const uint2*)&Ps[qs * PW + g * P_HEAD + lo * P_ROW + 4 * i - 4];
        } else {
          bb.u2[0] = carry;   // cell 2w+1 cols 8w..8w+3 == cell 2w's high half
        }
        bb.u2[1] = *(const uint2*)&Ps[qs * PW + g * P_HEAD + lo * P_ROW + 4 * i];
        carry = bb.u2[1];
        ffrag4 z = {0.f, 0.f, 0.f, 0.f};
        ffrag4 d = __builtin_amdgcn_mfma_f32_16x16x32_bf16(wfrag, bb.f8, z, 0, 0, 0);
        float a2v[4];
        if (edge) {
#pragma unroll
          for (int r = 0; r < 4; r++) {
            const int mp = m0 - 2 + 4 * i + r;
            float y = d[r] * sfv + tfv;
            float v = y * sigmoid_fast(y);
            a2v[r] = (mp >= 0 && mp < NAa) ? v : 0.0f;
          }
        } else {
#pragma unroll
          for (int r = 0; r < 4; r++) {
            float y = d[r] * sfv + tfv;
            a2v[r] = y * sigmoid_fast(y);
          }
        }
        uint2 pk;
        pk.x = pk2(a2v[0], a2v[1]);
        pk.y = pk2(a2v[2], a2v[3]);
        *(uint2*)&A2s[qs * AW + g * A_HEAD + lo * A_ROW + 4 * i] = pk;
      }
    }
    __syncthreads();
    // ---- phase 2: QK(t+1) -> Ps/Hb, then PV(t) reads A2s ----
    if (doqk) {
      if (realqk) {
#pragma unroll
        for (int qs = 0; qs < 2; ++qs) {
          ffrag4 cin = {linv[qs], linv[qs], linv[qs], linv[qs]};
          ffrag4 c0 = __builtin_amdgcn_mfma_f32_16x16x32_bf16(kf0, qf[qs], cin, 0, 0, 0);
          ffrag4 c1 = __builtin_amdgcn_mfma_f32_16x16x32_bf16(kf1, qf[qs], cin, 0, 0, 0);
          uint2 pk;
          pk.x = pk2(__builtin_amdgcn_exp2f(c0[0]), __builtin_amdgcn_exp2f(c0[1]));
          pk.y = pk2(__builtin_amdgcn_exp2f(c0[2]), __builtin_amdgcn_exp2f(c0[3]));
          *(uint2*)&Ps[qs * PW + h * P_HEAD + lo * P_ROW + 16 * (2 * u) + 4 * g] = pk;
          uint2 pk1;
          pk1.x = pk2(__builtin_amdgcn_exp2f(c1[0]), __builtin_amdgcn_exp2f(c1[1]));
          pk1.y = pk2(__builtin_amdgcn_exp2f(c1[2]), __builtin_amdgcn_exp2f(c1[3]));
          *(uint2*)&Ps[qs * PW + h * P_HEAD + lo * P_ROW + 16 * (2 * u + 1) + 4 * g] = pk1;
          if (u == 1 && g == 3)
            *(uint2*)&Hb[HB_IDX(par, qs, h, lo)] = pk1;   // halo for conv(t+2)
        }
      } else {
        uint2 zz; zz.x = 0; zz.y = 0;
#pragma unroll
        for (int qs = 0; qs < 2; ++qs) {
          *(uint2*)&Ps[qs * PW + h * P_HEAD + lo * P_ROW + 16 * (2 * u) + 4 * g] = zz;
          *(uint2*)&Ps[qs * PW + h * P_HEAD + lo * P_ROW + 16 * (2 * u + 1) + 4 * g] = zz;
        }
      }
    }
    // PV(t): head h, k-half u, both qsubs (V frags shared)
#pragma unroll
    for (int qs = 0; qs < 2; ++qs) {
      cvt16 av;
      av.u2[0] = *(const uint2*)&A2s[qs * AW + h * A_HEAD + lo * A_ROW + 32 * u + 8 * g];
      av.u2[1] = *(const uint2*)&A2s[qs * AW + h * A_HEAD + lo * A_ROW + 32 * u + 8 * g + 4];
      oacc[qs][0] = __builtin_amdgcn_mfma_f32_16x16x32_bf16(av.f8, vf0, oacc[qs][0], 0, 0, 0);
      oacc[qs][1] = __builtin_amdgcn_mfma_f32_16x16x32_bf16(av.f8, vf1, oacc[qs][1], 0, 0, 0);
    }
    __syncthreads();
  }

  // ---- cross-u reduction via A2s scratch, write o_part [split][be][n][c] bf16 ----
  float* scr = (float*)A2s;
  if (u == 1) {
#pragma unroll
    for (int qs = 0; qs < 2; ++qs) {
      float4 f0; f0.x = oacc[qs][0][0]; f0.y = oacc[qs][0][1]; f0.z = oacc[qs][0][2]; f0.w = oacc[qs][0][3];
      float4 f1; f1.x = oacc[qs][1][0]; f1.y = oacc[qs][1][1]; f1.z = oacc[qs][1][2]; f1.w = oacc[qs][1][3];
      *(float4*)&scr[((qs * 4 + h) * 64 + lane) * 8] = f0;
      *(float4*)&scr[((qs * 4 + h) * 64 + lane) * 8 + 4] = f1;
    }
  }
  __syncthreads();
  if (u == 0) {
#pragma unroll
    for (int qs = 0; qs < 2; ++qs) {
      const float4 f0 = *(const float4*)&scr[((qs * 4 + h) * 64 + lane) * 8];
      const float4 f1 = *(const float4*)&scr[((qs * 4 + h) * 64 + lane) * 8 + 4];
      const float fa[4] = {f0.x, f0.y, f0.z, f0.w};
      const float fb[4] = {f1.x, f1.y, f1.z, f1.w};
#pragma unroll
      for (int r = 0; r < 4; r++) {
        const size_t rowoff = ((size_t)(split * 8 + be) * NAa + n0 + 16 * qs + 4 * g + r) * CC;
        o_part[rowoff + h * HD + lo] = f2bf(oacc[qs][0][r] + fa[r]);
        o_part[rowoff + h * HD + 16 + lo] = f2bf(oacc[qs][1][r] + fb[r]);
      }
    }
  }
}

// ---- K3: out as MFMA GEMM + SiLU-gate + residual (sums 3 o_part splits) ----
__global__ __launch_bounds__(256) void out_kernel(
    const unsigned short* __restrict__ o_part, const unsigned short* __restrict__ wob,
    const float* __restrict__ t_out, const float* __restrict__ x,
    float* __restrict__ out) {
  const int tid = threadIdx.x;
  const int w = tid >> 6, lane = tid & 63, lo = lane & 15, g = lane >> 4;
  const int blk = blockIdx.x;
  const int b = blk / 400, pt = blk - b * 400;
  const int ng0 = pt * 16;
  const int a = ng0 / NAa, na0 = ng0 - a * NAa;
  const int be = b * 4 + a;
  const size_t orow0 = ((size_t)(0 * 8 + be) * NAa + na0 + lo) * CC;
  const size_t orow1 = ((size_t)(1 * 8 + be) * NAa + na0 + lo) * CC;
  const size_t orow2 = ((size_t)(2 * 8 + be) * NAa + na0 + lo) * CC;
  bfrag8 bf0[4], bf1[4], bf2[4];
#pragma unroll
  for (int kk = 0; kk < 4; kk++) {
    bf0[kk] = *(const bfrag8*)&o_part[orow0 + kk * 32 + g * 8];
    bf1[kk] = *(const bfrag8*)&o_part[orow1 + kk * 32 + g * 8];
    bf2[kk] = *(const bfrag8*)&o_part[orow2 + kk * 32 + g * 8];
  }
#pragma unroll
  for (int mt2 = 0; mt2 < 2; mt2++) {
    const int rowbase = (w * 2 + mt2) * 16;
    ffrag4 d = {0.f, 0.f, 0.f, 0.f};
#pragma unroll
    for (int kk = 0; kk < 4; kk++) {
      bfrag8 af = *(const bfrag8*)&wob[(size_t)(rowbase + lo) * CC + kk * 32 + g * 8];
      d = __builtin_amdgcn_mfma_f32_16x16x32_bf16(af, bf0[kk], d, 0, 0, 0);
      d = __builtin_amdgcn_mfma_f32_16x16x32_bf16(af, bf1[kk], d, 0, 0, 0);
      d = __builtin_amdgcn_mfma_f32_16x16x32_bf16(af, bf2[kk], d, 0, 0, 0);
    }
    const int ch0 = rowbase + 4 * g;
    const uint2 q0 = *(const uint2*)&o_part[orow0 + ch0];
    const uint2 q1 = *(const uint2*)&o_part[orow1 + ch0];
    const uint2 q2 = *(const uint2*)&o_part[orow2 + ch0];
    float ov[4] = {bfl(q0.x) + bfl(q1.x) + bfl(q2.x), bfh(q0.x) + bfh(q1.x) + bfh(q2.x),
                   bfl(q0.y) + bfl(q1.y) + bfl(q2.y), bfh(q0.y) + bfh(q1.y) + bfh(q2.y)};
#pragma unroll
    for (int r = 0; r < 4; r++) {
      const size_t xi = ((size_t)b * CC + ch0 + r) * NN + ng0 + lo;
      float y = d[r] + t_out[ch0 + r];
      out[xi] = ov[r] * sigmoid_fast(y) + x[xi];
    }
  }
}

extern "C" void kernel_launch(void* const* d_in, const int* in_sizes, int n_in,
                              void* d_out, int out_size, void* d_ws, size_t ws_size,
                              hipStream_t stream) {
  const float* x    = (const float*)d_in[0];
  const float* w_qk = (const float*)d_in[1];
  const float* s_qk = (const float*)d_in[2];
  const float* t_qk = (const float*)d_in[3];
  const float* w_in = (const float*)d_in[4];
  const float* s_in = (const float*)d_in[5];
  const float* t_in = (const float*)d_in[6];
  const float* w_out = (const float*)d_in[7];
  const float* s_out = (const float*)d_in[8];
  const float* t_out = (const float*)d_in[9];
  const float* w_fg = (const float*)d_in[10];
  const float* s_fg = (const float*)d_in[11];
  const float* t_fg = (const float*)d_in[12];

  char* wsb = (char*)d_ws;
  unsigned short* o_part = (unsigned short*)wsb;               // 9,830,400 B  [3 split][be][n][c] bf16
  unsigned short* vb_raw = (unsigned short*)(wsb + 9830400);   // 3,276,864 B
  unsigned short* vbp = vb_raw + 2;
  unsigned short* qt = (unsigned short*)(wsb + 13107264);      // 3,276,800 B
  unsigned short* kt = (unsigned short*)(wsb + 16384064);      // 3,276,800 B
  unsigned short* wqkb = (unsigned short*)(wsb + 19660864);    //    98,304 B
  unsigned short* wob = (unsigned short*)(wsb + 19759168);     //    32,768 B
  float* pstats = (float*)(wsb + 19791936);                    // 3,276,800 B [4 ks][be][h][n] -> total 23,068,736 B
  float* out = (float*)d_out;

  prep_kernel<<<10, 256, 0, stream>>>(w_qk, s_qk, w_in, s_in, w_out, s_out, wqkb, wob);
  qkv_kernel<<<800, 256, 0, stream>>>(x, wqkb, t_qk, t_in, qt, kt, vbp);
  stats_kernel<<<800, 256, 0, stream>>>(qt, kt, pstats);
  apply_kernel<<<1200, 512, 0, stream>>>(qt, kt, vbp, pstats, w_fg, s_fg, t_fg, o_part);
  out_kernel<<<800, 256, 0, stream>>>(o_part, wob, t_out, x, out);
}

// Round 11
// 117.820 us; speedup vs baseline: 1.1321x; 1.0083x over previous
//
#include <hip/hip_runtime.h>
#include <hip/hip_bf16.h>
#include <cstdint>

#define CC 128
#define NN 6400
#define NAa 1600
#define HEADS 4
#define HD 32
#define NB 32
#define MT 64

#define P_ROW 68
#define P_HEAD 1096   // 16*68+8 pad
#define A_ROW 76
#define A_HEAD 1224   // 16*76+8 pad
#define PW (HEADS * P_HEAD)   // 4384 elems per q-subtile
#define AW (HEADS * A_HEAD)   // 4896 elems per q-subtile
// halo buffer: [parity][qs][h][lo][4] bf16
#define HB_IDX(par, qs, hh, lo) (((((par)*2 + (qs))*4 + (hh))*16 + (lo)) * 4)
#define XROW 136              // qkv LDS x-tile row stride (16B-aligned: 272 B)

typedef __attribute__((ext_vector_type(8))) short bfrag8;
typedef __attribute__((ext_vector_type(4))) float ffrag4;
typedef union { uint2 u2[2]; bfrag8 f8; } cvt16;

#define LOG2E 1.4426950408889634f
#define QSCL (0.17677669529663687f * 1.4426950408889634f)

__device__ __forceinline__ float sigmoid_fast(float y) {
  return __builtin_amdgcn_rcpf(1.0f + __builtin_amdgcn_exp2f(-LOG2E * y));
}
__device__ __forceinline__ unsigned short f2bf(float f) {
  unsigned u = __float_as_uint(f);
  return (unsigned short)((u + 0x7FFFu + ((u >> 16) & 1u)) >> 16);
}
// packed 2xf32 -> 2xbf16 (RNE) — should emit v_cvt_pk_bf16_f32
__device__ __forceinline__ unsigned pk2(float a, float b) {
  float2 f2; f2.x = a; f2.y = b;
  __hip_bfloat162 h = __float22bfloat162_rn(f2);
  union { __hip_bfloat162 h2; unsigned u; } cv; cv.h2 = h;
  return cv.u;
}
__device__ __forceinline__ float bfl(unsigned u) { return __uint_as_float(u << 16); }
__device__ __forceinline__ float bfh(unsigned u) { return __uint_as_float(u & 0xFFFF0000u); }

// ---- K0: prep — weights->bf16 with scales folded (x-transpose fused into qkv) ----
__global__ __launch_bounds__(256) void prep_kernel(
    const float* __restrict__ w_qk, const float* __restrict__ s_qk,
    const float* __restrict__ w_in, const float* __restrict__ s_in,
    const float* __restrict__ w_out, const float* __restrict__ s_out,
    unsigned short* __restrict__ wqkb, unsigned short* __restrict__ wob) {
  const int blk = blockIdx.x, tid = threadIdx.x;
  if (blk < 8) {
    const int r0 = blk * 48;
    for (int i = tid; i < 6144; i += 256) {
      int r = r0 + (i >> 7), c = i & 127;
      float wv, sv;
      if (r < 2 * CC) { wv = w_qk[r * CC + c]; sv = s_qk[r] * (r < CC ? QSCL : 1.0f); }
      else           { wv = w_in[(r - 2 * CC) * CC + c]; sv = s_in[r - 2 * CC]; }
      wqkb[r * CC + c] = f2bf(wv * sv);
    }
  } else {
    const int r0 = (blk - 8) * 64;
    for (int i = tid; i < 8192; i += 256) {
      int r = r0 + (i >> 7), c = i & 127;
      wob[r * CC + c] = f2bf(w_out[r * CC + c] * s_out[r]);
    }
  }
}

// ---- K1: qkv as MFMA GEMM (384 x 6400 x K=128), 32 pixels/block:
//      each weight af-fragment feeds TWO MFMAs (R10 stats-widening lever). ----
__global__ __launch_bounds__(256) void qkv_kernel(
    const float* __restrict__ x, const unsigned short* __restrict__ wqkb,
    const float* __restrict__ t_qk, const float* __restrict__ t_in,
    unsigned short* __restrict__ qt, unsigned short* __restrict__ kt,
    unsigned short* __restrict__ vb) {
  __shared__ __align__(16) unsigned short xb[32 * XROW];  // 8704 B
  const int tid = threadIdx.x;
  const int w = tid >> 6, lane = tid & 63, lo = lane & 15, g = lane >> 4;
  const int blk = blockIdx.x;
  const int b = blk / 200, pt = blk - b * 200;
  const int ng0 = pt * 32;
  const int a = ng0 / NAa, na0 = ng0 - a * NAa;
  const int be = b * 4 + a;
  // ---- stage: transpose x[b][c][ng0..ng0+31] f32 -> xb[n][c] bf16 ----
  {
    const int c = tid >> 1, half = tid & 1;
    const float* xr = &x[((size_t)(b * CC + c)) * NN + ng0 + 16 * half];
    const float4 f0 = *(const float4*)xr;
    const float4 f1 = *(const float4*)(xr + 4);
    const float4 f2 = *(const float4*)(xr + 8);
    const float4 f3 = *(const float4*)(xr + 12);
    unsigned short* dst = &xb[(16 * half) * XROW + c];
    dst[0 * XROW] = f2bf(f0.x); dst[1 * XROW] = f2bf(f0.y);
    dst[2 * XROW] = f2bf(f0.z); dst[3 * XROW] = f2bf(f0.w);
    dst[4 * XROW] = f2bf(f1.x); dst[5 * XROW] = f2bf(f1.y);
    dst[6 * XROW] = f2bf(f1.z); dst[7 * XROW] = f2bf(f1.w);
    dst[8 * XROW] = f2bf(f2.x); dst[9 * XROW] = f2bf(f2.y);
    dst[10 * XROW] = f2bf(f2.z); dst[11 * XROW] = f2bf(f2.w);
    dst[12 * XROW] = f2bf(f3.x); dst[13 * XROW] = f2bf(f3.y);
    dst[14 * XROW] = f2bf(f3.z); dst[15 * XROW] = f2bf(f3.w);
  }
  __syncthreads();
  bfrag8 bf[2][4];
#pragma unroll
  for (int qs = 0; qs < 2; qs++)
#pragma unroll
    for (int kk = 0; kk < 4; kk++)
      bf[qs][kk] = *(const bfrag8*)&xb[(16 * qs + lo) * XROW + kk * 32 + g * 8];
#pragma unroll
  for (int mt6 = 0; mt6 < 6; mt6++) {
    const int rowbase = (w * 6 + mt6) * 16;
    ffrag4 d0 = {0.f, 0.f, 0.f, 0.f};
    ffrag4 d1 = {0.f, 0.f, 0.f, 0.f};
#pragma unroll
    for (int kk = 0; kk < 4; kk++) {
      bfrag8 af = *(const bfrag8*)&wqkb[(size_t)(rowbase + lo) * CC + kk * 32 + g * 8];
      d0 = __builtin_amdgcn_mfma_f32_16x16x32_bf16(af, bf[0][kk], d0, 0, 0, 0);
      d1 = __builtin_amdgcn_mfma_f32_16x16x32_bf16(af, bf[1][kk], d1, 0, 0, 0);
    }
    const int r0c = rowbase + 4 * g;
#pragma unroll
    for (int qs = 0; qs < 2; qs++) {
      const ffrag4 d = qs ? d1 : d0;
      const int na = na0 + 16 * qs;
      if (r0c < CC) {
        const int h = r0c >> 5, dd0 = r0c & 31;
        uint2 pk;
        pk.x = pk2(d[0] + t_qk[r0c] * QSCL, d[1] + t_qk[r0c + 1] * QSCL);
        pk.y = pk2(d[2] + t_qk[r0c + 2] * QSCL, d[3] + t_qk[r0c + 3] * QSCL);
        *(uint2*)&qt[((size_t)(be * HEADS + h) * NAa + na + lo) * HD + dd0] = pk;
      } else if (r0c < 2 * CC) {
        const int ch = r0c - CC, h = ch >> 5, dd0 = ch & 31;
        uint2 pk;
        pk.x = pk2(d[0] + t_qk[r0c], d[1] + t_qk[r0c + 1]);
        pk.y = pk2(d[2] + t_qk[r0c + 2], d[3] + t_qk[r0c + 3]);
        *(uint2*)&kt[((size_t)(be * HEADS + h) * NAa + na + lo) * HD + dd0] = pk;
      } else {
        const int ch0 = r0c - 2 * CC;
        const uint2 xv = *(const uint2*)&xb[(16 * qs + lo) * XROW + ch0];
        float xr[4] = {bfl(xv.x), bfh(xv.x), bfl(xv.y), bfh(xv.y)};
#pragma unroll
        for (int r = 0; r < 4; r++) {
          float y = d[r] + t_in[ch0 + r];
          vb[((size_t)be * CC + ch0 + r) * NAa + na + lo] = f2bf(sigmoid_fast(y) * xr[r]);
        }
      }
    }
  }
}

// ---- K2a: partial softmax denominators (M0 = 0, q pre-scaled) ----
//      64 queries x 4 key-splits per block (grid stays 800 -> occupancy kept):
//      each kf B-fragment feeds FOUR MFMAs, halving K loads + addressing again.
__global__ __launch_bounds__(256) void stats_kernel(
    const unsigned short* __restrict__ qt, const unsigned short* __restrict__ kt,
    float* __restrict__ pstats) {
  int tid = threadIdx.x;
  int h = tid >> 6, lane = tid & 63, lo = lane & 15, g = lane >> 4;
  int bid = blockIdx.x;
  int be = bid & 7;
  int rest = bid >> 3;            // 0..99
  int n0 = (rest % 25) * 64;
  int ks = rest / 25;             // 0..3
  int ts0 = (ks == 0) ? 0 : (ks == 1 ? 7 : (ks == 2 ? 13 : 19));
  int ts1 = (ks == 0) ? 7 : (ks == 1 ? 13 : (ks == 2 ? 19 : 25));

  const unsigned short* qtb = qt + (size_t)(be * HEADS + h) * NAa * HD;
  const unsigned short* ktb = kt + (size_t)(be * HEADS + h) * NAa * HD;

  bfrag8 qf[4];
#pragma unroll
  for (int qq = 0; qq < 4; qq++)
    qf[qq] = *(const bfrag8*)(qtb + (size_t)(n0 + 16 * qq + lo) * HD + g * 8);
  float sm[4][4];
#pragma unroll
  for (int qq = 0; qq < 4; qq++)
#pragma unroll
    for (int r = 0; r < 4; r++) sm[qq][r] = 0.f;

  for (int t = ts0; t < ts1; t++) {
    int m0 = t * MT;
#pragma unroll
    for (int sb = 0; sb < 4; sb++) {
      bfrag8 kf = *(const bfrag8*)(ktb + (size_t)(m0 + sb * 16 + lo) * HD + g * 8);
#pragma unroll
      for (int qq = 0; qq < 4; qq++) {
        ffrag4 z = {0.f, 0.f, 0.f, 0.f};
        ffrag4 c = __builtin_amdgcn_mfma_f32_16x16x32_bf16(qf[qq], kf, z, 0, 0, 0);
#pragma unroll
        for (int r = 0; r < 4; r++) sm[qq][r] += __builtin_amdgcn_exp2f(c[r]);
      }
    }
  }
#pragma unroll
  for (int qq = 0; qq < 4; qq++)
#pragma unroll
    for (int r = 0; r < 4; r++) {
#pragma unroll
      for (int off = 1; off <= 8; off <<= 1) sm[qq][r] += __shfl_xor(sm[qq][r], off);
    }
  if (lo == 0) {
#pragma unroll
    for (int qq = 0; qq < 4; qq++) {
      float4 s4; s4.x = sm[qq][0]; s4.y = sm[qq][1]; s4.z = sm[qq][2]; s4.w = sm[qq][3];
      *(float4*)&pstats[((size_t)(ks * 8 + be) * HEADS + h) * NAa + n0 + 16 * qq + 4 * g] = s4;
    }
  }
}

// ---- K2b: apply — R7 structure (512 thr, NB=32, single-buffered P + parity
//      halo Hb, 3-WAY key split, grid 1200 — R9 proved 4-way regresses).
//      conv carries the overlapping uint2 (R10). No setprio (R6). ----
__global__ __launch_bounds__(512) void apply_kernel(
    const unsigned short* __restrict__ qt, const unsigned short* __restrict__ kt,
    const unsigned short* __restrict__ vb, const float* __restrict__ pstats,
    const float* __restrict__ w_fg, const float* __restrict__ s_fg,
    const float* __restrict__ t_fg, unsigned short* __restrict__ o_part) {
  __shared__ __align__(16) unsigned short Ps[2 * PW];   // 17536 B
  __shared__ __align__(16) unsigned short A2s[2 * AW];  // 19584 B
  __shared__ __align__(16) unsigned short Hb[1024];     //  2048 B halo [par][qs][h][lo][4]
  const int tid = threadIdx.x;
  const int w = tid >> 6, lane = tid & 63, lo = lane & 15, g = lane >> 4;
  const int h = w >> 1, u = w & 1;
  const int bid = blockIdx.x;
  const int be = bid & 7;
  const int rest = bid >> 3;
  const int n0 = (rest % 50) * NB;
  const int split = rest / 50;                         // 0..2
  const int ts0 = (split == 0) ? 0 : (split == 1 ? 9 : 17);
  const int tend = (split == 0) ? 9 : (split == 1 ? 17 : 26);  // t=25 virtual tail
  const int p0 = ts0 & 1;

  const unsigned short* qtb = qt + (size_t)(be * HEADS + h) * NAa * HD;
  const unsigned short* ktb = kt + (size_t)(be * HEADS + h) * NAa * HD;
  const unsigned short* vhb = vb + (size_t)(be * CC + h * HD) * NAa;

  bfrag8 qf[2];
#pragma unroll
  for (int qs = 0; qs < 2; ++qs)
    qf[qs] = *(const bfrag8*)(qtb + (size_t)(n0 + 16 * qs + lo) * HD + g * 8);

  // conv-weight A-fragment (constant): row=lo=(ho*4+s), k=g*8+j
  bfrag8 wfrag;
  {
    const int ho = lo >> 2, s = lo & 3;
#pragma unroll
    for (int j = 0; j < 8; j++) {
      const int tp = j - s;
      float wv = (tp >= 0 && tp < 5) ? w_fg[(ho * HEADS + g) * 5 + tp] : 0.0f;
      wfrag[j] = (short)f2bf(wv);
    }
  }
  const float sfv = s_fg[g], tfv = t_fg[g];

  // -log2(denominator) per q-subtile (4 key-split partials), folded into MFMA C-in
  float linv[2];
#pragma unroll
  for (int qs = 0; qs < 2; ++qs) {
    float den = 0.f;
#pragma unroll
    for (int ks = 0; ks < 4; ++ks)
      den += pstats[((size_t)(ks * 8 + be) * HEADS + h) * NAa + n0 + 16 * qs + lo];
    linv[qs] = -__log2f(den);
  }

  ffrag4 oacc[2][2];
#pragma unroll
  for (int qs = 0; qs < 2; ++qs) {
    ffrag4 z = {0.f, 0.f, 0.f, 0.f};
    oacc[qs][0] = z; oacc[qs][1] = z;
  }

  // ---- prologue: Hb[p0] = halo for conv(ts0) ----
  if (split == 0) {
    if (u == 0 && g == 0) {
      uint2 zz; zz.x = 0; zz.y = 0;
#pragma unroll
      for (int qs = 0; qs < 2; ++qs)
        *(uint2*)&Hb[HB_IDX(p0, qs, h, lo)] = zz;
    }
  } else if (u == 0) {
    // halo keys ts0*64-4..-1 from K rows ts0*64-16..-1 (g==3 lanes hold them)
    bfrag8 kf = *(const bfrag8*)(ktb + (size_t)(ts0 * MT - 16 + lo) * HD + g * 8);
#pragma unroll
    for (int qs = 0; qs < 2; ++qs) {
      ffrag4 cin = {linv[qs], linv[qs], linv[qs], linv[qs]};
      ffrag4 c = __builtin_amdgcn_mfma_f32_16x16x32_bf16(kf, qf[qs], cin, 0, 0, 0);
      if (g == 3) {
        uint2 pk;
        pk.x = pk2(__builtin_amdgcn_exp2f(c[0]), __builtin_amdgcn_exp2f(c[1]));
        pk.y = pk2(__builtin_amdgcn_exp2f(c[2]), __builtin_amdgcn_exp2f(c[3]));
        *(uint2*)&Hb[HB_IDX(p0, qs, h, lo)] = pk;
      }
    }
  }
  // ---- prologue: QK(ts0) -> Ps; sb==3/g==3 lanes also feed Hb[p0^1] ----
  {
    const int m0 = ts0 * MT;
#pragma unroll
    for (int sbi = 0; sbi < 2; sbi++) {
      const int sb = 2 * u + sbi;
      bfrag8 kf = *(const bfrag8*)(ktb + (size_t)(m0 + sb * 16 + lo) * HD + g * 8);
#pragma unroll
      for (int qs = 0; qs < 2; ++qs) {
        ffrag4 cin = {linv[qs], linv[qs], linv[qs], linv[qs]};
        ffrag4 c = __builtin_amdgcn_mfma_f32_16x16x32_bf16(kf, qf[qs], cin, 0, 0, 0);
        uint2 pk;
        pk.x = pk2(__builtin_amdgcn_exp2f(c[0]), __builtin_amdgcn_exp2f(c[1]));
        pk.y = pk2(__builtin_amdgcn_exp2f(c[2]), __builtin_amdgcn_exp2f(c[3]));
        *(uint2*)&Ps[qs * PW + h * P_HEAD + lo * P_ROW + 16 * sb + 4 * g] = pk;
        if (sb == 3 && g == 3)
          *(uint2*)&Hb[HB_IDX(p0 ^ 1, qs, h, lo)] = pk;
      }
    }
  }
  __syncthreads();

  for (int t = ts0; t < tend; t++) {
    const int m0 = t * MT;
    const int par = t & 1;
    // early V loads (k-half u) for PV(t) — shared across q-subtiles
    const bfrag8 vf0 = *(const bfrag8*)(vhb + (size_t)lo * NAa + (m0 - 2 + 32 * u + 8 * g));
    const bfrag8 vf1 = *(const bfrag8*)(vhb + (size_t)(16 + lo) * NAa + (m0 - 2 + 32 * u + 8 * g));
    const bool doqk = (t + 1 < tend);
    const bool realqk = doqk && (t + 1 < 25);
    bfrag8 kf0, kf1;
    if (realqk) {
      const int m1 = (t + 1) * MT;
      kf0 = *(const bfrag8*)(ktb + (size_t)(m1 + (2 * u) * 16 + lo) * HD + g * 8);
      kf1 = *(const bfrag8*)(ktb + (size_t)(m1 + (2 * u + 1) * 16 + lo) * HD + g * 8);
    }
    // ---- phase 1: conv(t) reads Ps/Hb -> writes A2s (carry overlapping uint2) ----
    const bool edge = (t == 0) || (t == 25);
#pragma unroll
    for (int qs = 0; qs < 2; ++qs) {
      uint2 carry;
#pragma unroll
      for (int ii = 0; ii < 2; ii++) {
        const int i = 2 * w + ii;
        cvt16 bb;
        if (ii == 0) {
          if (i == 0)
            bb.u2[0] = *(const uint2*)&Hb[HB_IDX(par, qs, g, lo)];
          else
            bb.u2[0] = *(const uint2*)&Ps[qs * PW + g * P_HEAD + lo * P_ROW + 4 * i - 4];
        } else {
          bb.u2[0] = carry;   // cell 2w+1 cols 8w..8w+3 == cell 2w's high half
        }
        bb.u2[1] = *(const uint2*)&Ps[qs * PW + g * P_HEAD + lo * P_ROW + 4 * i];
        carry = bb.u2[1];
        ffrag4 z = {0.f, 0.f, 0.f, 0.f};
        ffrag4 d = __builtin_amdgcn_mfma_f32_16x16x32_bf16(wfrag, bb.f8, z, 0, 0, 0);
        float a2v[4];
        if (edge) {
#pragma unroll
          for (int r = 0; r < 4; r++) {
            const int mp = m0 - 2 + 4 * i + r;
            float y = d[r] * sfv + tfv;
            float v = y * sigmoid_fast(y);
            a2v[r] = (mp >= 0 && mp < NAa) ? v : 0.0f;
          }
        } else {
#pragma unroll
          for (int r = 0; r < 4; r++) {
            float y = d[r] * sfv + tfv;
            a2v[r] = y * sigmoid_fast(y);
          }
        }
        uint2 pk;
        pk.x = pk2(a2v[0], a2v[1]);
        pk.y = pk2(a2v[2], a2v[3]);
        *(uint2*)&A2s[qs * AW + g * A_HEAD + lo * A_ROW + 4 * i] = pk;
      }
    }
    __syncthreads();
    // ---- phase 2: QK(t+1) -> Ps/Hb, then PV(t) reads A2s ----
    if (doqk) {
      if (realqk) {
#pragma unroll
        for (int qs = 0; qs < 2; ++qs) {
          ffrag4 cin = {linv[qs], linv[qs], linv[qs], linv[qs]};
          ffrag4 c0 = __builtin_amdgcn_mfma_f32_16x16x32_bf16(kf0, qf[qs], cin, 0, 0, 0);
          ffrag4 c1 = __builtin_amdgcn_mfma_f32_16x16x32_bf16(kf1, qf[qs], cin, 0, 0, 0);
          uint2 pk;
          pk.x = pk2(__builtin_amdgcn_exp2f(c0[0]), __builtin_amdgcn_exp2f(c0[1]));
          pk.y = pk2(__builtin_amdgcn_exp2f(c0[2]), __builtin_amdgcn_exp2f(c0[3]));
          *(uint2*)&Ps[qs * PW + h * P_HEAD + lo * P_ROW + 16 * (2 * u) + 4 * g] = pk;
          uint2 pk1;
          pk1.x = pk2(__builtin_amdgcn_exp2f(c1[0]), __builtin_amdgcn_exp2f(c1[1]));
          pk1.y = pk2(__builtin_amdgcn_exp2f(c1[2]), __builtin_amdgcn_exp2f(c1[3]));
          *(uint2*)&Ps[qs * PW + h * P_HEAD + lo * P_ROW + 16 * (2 * u + 1) + 4 * g] = pk1;
          if (u == 1 && g == 3)
            *(uint2*)&Hb[HB_IDX(par, qs, h, lo)] = pk1;   // halo for conv(t+2)
        }
      } else {
        uint2 zz; zz.x = 0; zz.y = 0;
#pragma unroll
        for (int qs = 0; qs < 2; ++qs) {
          *(uint2*)&Ps[qs * PW + h * P_HEAD + lo * P_ROW + 16 * (2 * u) + 4 * g] = zz;
          *(uint2*)&Ps[qs * PW + h * P_HEAD + lo * P_ROW + 16 * (2 * u + 1) + 4 * g] = zz;
        }
      }
    }
    // PV(t): head h, k-half u, both qsubs (V frags shared)
#pragma unroll
    for (int qs = 0; qs < 2; ++qs) {
      cvt16 av;
      av.u2[0] = *(const uint2*)&A2s[qs * AW + h * A_HEAD + lo * A_ROW + 32 * u + 8 * g];
      av.u2[1] = *(const uint2*)&A2s[qs * AW + h * A_HEAD + lo * A_ROW + 32 * u + 8 * g + 4];
      oacc[qs][0] = __builtin_amdgcn_mfma_f32_16x16x32_bf16(av.f8, vf0, oacc[qs][0], 0, 0, 0);
      oacc[qs][1] = __builtin_amdgcn_mfma_f32_16x16x32_bf16(av.f8, vf1, oacc[qs][1], 0, 0, 0);
    }
    __syncthreads();
  }

  // ---- cross-u reduction via A2s scratch, write o_part [split][be][n][c] bf16 ----
  float* scr = (float*)A2s;
  if (u == 1) {
#pragma unroll
    for (int qs = 0; qs < 2; ++qs) {
      float4 f0; f0.x = oacc[qs][0][0]; f0.y = oacc[qs][0][1]; f0.z = oacc[qs][0][2]; f0.w = oacc[qs][0][3];
      float4 f1; f1.x = oacc[qs][1][0]; f1.y = oacc[qs][1][1]; f1.z = oacc[qs][1][2]; f1.w = oacc[qs][1][3];
      *(float4*)&scr[((qs * 4 + h) * 64 + lane) * 8] = f0;
      *(float4*)&scr[((qs * 4 + h) * 64 + lane) * 8 + 4] = f1;
    }
  }
  __syncthreads();
  if (u == 0) {
#pragma unroll
    for (int qs = 0; qs < 2; ++qs) {
      const float4 f0 = *(const float4*)&scr[((qs * 4 + h) * 64 + lane) * 8];
      const float4 f1 = *(const float4*)&scr[((qs * 4 + h) * 64 + lane) * 8 + 4];
      const float fa[4] = {f0.x, f0.y, f0.z, f0.w};
      const float fb[4] = {f1.x, f1.y, f1.z, f1.w};
#pragma unroll
      for (int r = 0; r < 4; r++) {
        const size_t rowoff = ((size_t)(split * 8 + be) * NAa + n0 + 16 * qs + 4 * g + r) * CC;
        o_part[rowoff + h * HD + lo] = f2bf(oacc[qs][0][r] + fa[r]);
        o_part[rowoff + h * HD + 16 + lo] = f2bf(oacc[qs][1][r] + fb[r]);
      }
    }
  }
}

// ---- K3: out as MFMA GEMM + SiLU-gate + residual, 32 pixels/block
//      (two q-subtiles processed sequentially to keep VGPR <=128). ----
__global__ __launch_bounds__(256) void out_kernel(
    const unsigned short* __restrict__ o_part, const unsigned short* __restrict__ wob,
    const float* __restrict__ t_out, const float* __restrict__ x,
    float* __restrict__ out) {
  const int tid = threadIdx.x;
  const int w = tid >> 6, lane = tid & 63, lo = lane & 15, g = lane >> 4;
  const int blk = blockIdx.x;
  const int b = blk / 200, pt = blk - b * 200;
  const int ng0 = pt * 32;
  const int a = ng0 / NAa, na0 = ng0 - a * NAa;
  const int be = b * 4 + a;
#pragma unroll
  for (int qs = 0; qs < 2; qs++) {
    size_t orow[3];
#pragma unroll
    for (int s = 0; s < 3; s++)
      orow[s] = ((size_t)(s * 8 + be) * NAa + na0 + 16 * qs + lo) * CC;
    bfrag8 bfs[3][4];
#pragma unroll
    for (int s = 0; s < 3; s++)
#pragma unroll
      for (int kk = 0; kk < 4; kk++)
        bfs[s][kk] = *(const bfrag8*)&o_part[orow[s] + kk * 32 + g * 8];
#pragma unroll
    for (int mt2 = 0; mt2 < 2; mt2++) {
      const int rowbase = (w * 2 + mt2) * 16;
      ffrag4 d = {0.f, 0.f, 0.f, 0.f};
#pragma unroll
      for (int kk = 0; kk < 4; kk++) {
        bfrag8 af = *(const bfrag8*)&wob[(size_t)(rowbase + lo) * CC + kk * 32 + g * 8];
#pragma unroll
        for (int s = 0; s < 3; s++)
          d = __builtin_amdgcn_mfma_f32_16x16x32_bf16(af, bfs[s][kk], d, 0, 0, 0);
      }
      const int ch0 = rowbase + 4 * g;
      float ov[4] = {0.f, 0.f, 0.f, 0.f};
#pragma unroll
      for (int s = 0; s < 3; s++) {
        const uint2 q = *(const uint2*)&o_part[orow[s] + ch0];
        ov[0] += bfl(q.x); ov[1] += bfh(q.x);
        ov[2] += bfl(q.y); ov[3] += bfh(q.y);
      }
#pragma unroll
      for (int r = 0; r < 4; r++) {
        const size_t xi = ((size_t)b * CC + ch0 + r) * NN + ng0 + 16 * qs + lo;
        float y = d[r] + t_out[ch0 + r];
        out[xi] = ov[r] * sigmoid_fast(y) + x[xi];
      }
    }
  }
}

extern "C" void kernel_launch(void* const* d_in, const int* in_sizes, int n_in,
                              void* d_out, int out_size, void* d_ws, size_t ws_size,
                              hipStream_t stream) {
  const float* x    = (const float*)d_in[0];
  const float* w_qk = (const float*)d_in[1];
  const float* s_qk = (const float*)d_in[2];
  const float* t_qk = (const float*)d_in[3];
  const float* w_in = (const float*)d_in[4];
  const float* s_in = (const float*)d_in[5];
  const float* t_in = (const float*)d_in[6];
  const float* w_out = (const float*)d_in[7];
  const float* s_out = (const float*)d_in[8];
  const float* t_out = (const float*)d_in[9];
  const float* w_fg = (const float*)d_in[10];
  const float* s_fg = (const float*)d_in[11];
  const float* t_fg = (const float*)d_in[12];

  char* wsb = (char*)d_ws;
  unsigned short* o_part = (unsigned short*)wsb;               // 9,830,400 B  [3 split][be][n][c] bf16
  unsigned short* vb_raw = (unsigned short*)(wsb + 9830400);   // 3,276,864 B
  unsigned short* vbp = vb_raw + 2;
  unsigned short* qt = (unsigned short*)(wsb + 13107264);      // 3,276,800 B
  unsigned short* kt = (unsigned short*)(wsb + 16384064);      // 3,276,800 B
  unsigned short* wqkb = (unsigned short*)(wsb + 19660864);    //    98,304 B
  unsigned short* wob = (unsigned short*)(wsb + 19759168);     //    32,768 B
  float* pstats = (float*)(wsb + 19791936);                    // 3,276,800 B [4 ks][be][h][n] -> total 23,068,736 B
  float* out = (float*)d_out;

  prep_kernel<<<10, 256, 0, stream>>>(w_qk, s_qk, w_in, s_in, w_out, s_out, wqkb, wob);
  qkv_kernel<<<400, 256, 0, stream>>>(x, wqkb, t_qk, t_in, qt, kt, vbp);
  stats_kernel<<<800, 256, 0, stream>>>(qt, kt, pstats);
  apply_kernel<<<1200, 512, 0, stream>>>(qt, kt, vbp, pstats, w_fg, s_fg, t_fg, o_part);
  out_kernel<<<400, 256, 0, stream>>>(o_part, wob, t_out, x, out);
}

// Round 12
// 117.456 us; speedup vs baseline: 1.1356x; 1.0031x over previous
//
#include <hip/hip_runtime.h>
#include <hip/hip_bf16.h>
#include <cstdint>

#define CC 128
#define NN 6400
#define NAa 1600
#define HEADS 4
#define HD 32
#define NB 32
#define MT 64

#define P_ROW 68
#define P_HEAD 1096   // 16*68+8 pad
#define A_ROW 76
#define A_HEAD 1224   // 16*76+8 pad
#define PW (HEADS * P_HEAD)   // 4384 elems per q-subtile
#define AW (HEADS * A_HEAD)   // 4896 elems per q-subtile
// halo buffer: [parity][qs][h][lo][4] bf16
#define HB_IDX(par, qs, hh, lo) (((((par)*2 + (qs))*4 + (hh))*16 + (lo)) * 4)
#define XROW 136              // qkv LDS x-tile row stride (16B-aligned: 272 B)

typedef __attribute__((ext_vector_type(8))) short bfrag8;
typedef __attribute__((ext_vector_type(4))) float ffrag4;
typedef union { uint2 u2[2]; bfrag8 f8; } cvt16;

#define LOG2E 1.4426950408889634f
#define QSCL (0.17677669529663687f * 1.4426950408889634f)

__device__ __forceinline__ float sigmoid_fast(float y) {
  return __builtin_amdgcn_rcpf(1.0f + __builtin_amdgcn_exp2f(-LOG2E * y));
}
__device__ __forceinline__ unsigned short f2bf(float f) {
  unsigned u = __float_as_uint(f);
  return (unsigned short)((u + 0x7FFFu + ((u >> 16) & 1u)) >> 16);
}
// packed 2xf32 -> 2xbf16 (RNE) — should emit v_cvt_pk_bf16_f32
__device__ __forceinline__ unsigned pk2(float a, float b) {
  float2 f2; f2.x = a; f2.y = b;
  __hip_bfloat162 h = __float22bfloat162_rn(f2);
  union { __hip_bfloat162 h2; unsigned u; } cv; cv.h2 = h;
  return cv.u;
}
__device__ __forceinline__ float bfl(unsigned u) { return __uint_as_float(u << 16); }
__device__ __forceinline__ float bfh(unsigned u) { return __uint_as_float(u & 0xFFFF0000u); }

// ---- K0: prep — weights->bf16 with scales folded (x-transpose fused into qkv) ----
__global__ __launch_bounds__(256) void prep_kernel(
    const float* __restrict__ w_qk, const float* __restrict__ s_qk,
    const float* __restrict__ w_in, const float* __restrict__ s_in,
    const float* __restrict__ w_out, const float* __restrict__ s_out,
    unsigned short* __restrict__ wqkb, unsigned short* __restrict__ wob) {
  const int blk = blockIdx.x, tid = threadIdx.x;
  if (blk < 8) {
    const int r0 = blk * 48;
    for (int i = tid; i < 6144; i += 256) {
      int r = r0 + (i >> 7), c = i & 127;
      float wv, sv;
      if (r < 2 * CC) { wv = w_qk[r * CC + c]; sv = s_qk[r] * (r < CC ? QSCL : 1.0f); }
      else           { wv = w_in[(r - 2 * CC) * CC + c]; sv = s_in[r - 2 * CC]; }
      wqkb[r * CC + c] = f2bf(wv * sv);
    }
  } else {
    const int r0 = (blk - 8) * 64;
    for (int i = tid; i < 8192; i += 256) {
      int r = r0 + (i >> 7), c = i & 127;
      wob[r * CC + c] = f2bf(w_out[r * CC + c] * s_out[r]);
    }
  }
}

// ---- K1: qkv as MFMA GEMM (384 x 6400 x K=128), 32 pixels/block.
//      vb writes now staged through LDS -> packed dword stores (full 64B rows)
//      instead of 1024 scalar 2B scattered stores per block. ----
__global__ __launch_bounds__(256) void qkv_kernel(
    const float* __restrict__ x, const unsigned short* __restrict__ wqkb,
    const float* __restrict__ t_qk, const float* __restrict__ t_in,
    unsigned short* __restrict__ qt, unsigned short* __restrict__ kt,
    unsigned short* __restrict__ vb) {
  __shared__ __align__(16) unsigned short xb[32 * XROW];    // 8704 B
  __shared__ __align__(16) unsigned short vstage[CC * 32];  // 8192 B
  const int tid = threadIdx.x;
  const int w = tid >> 6, lane = tid & 63, lo = lane & 15, g = lane >> 4;
  const int blk = blockIdx.x;
  const int b = blk / 200, pt = blk - b * 200;
  const int ng0 = pt * 32;
  const int a = ng0 / NAa, na0 = ng0 - a * NAa;
  const int be = b * 4 + a;
  // ---- stage: transpose x[b][c][ng0..ng0+31] f32 -> xb[n][c] bf16 ----
  {
    const int c = tid >> 1, half = tid & 1;
    const float* xr = &x[((size_t)(b * CC + c)) * NN + ng0 + 16 * half];
    const float4 f0 = *(const float4*)xr;
    const float4 f1 = *(const float4*)(xr + 4);
    const float4 f2 = *(const float4*)(xr + 8);
    const float4 f3 = *(const float4*)(xr + 12);
    unsigned short* dst = &xb[(16 * half) * XROW + c];
    dst[0 * XROW] = f2bf(f0.x); dst[1 * XROW] = f2bf(f0.y);
    dst[2 * XROW] = f2bf(f0.z); dst[3 * XROW] = f2bf(f0.w);
    dst[4 * XROW] = f2bf(f1.x); dst[5 * XROW] = f2bf(f1.y);
    dst[6 * XROW] = f2bf(f1.z); dst[7 * XROW] = f2bf(f1.w);
    dst[8 * XROW] = f2bf(f2.x); dst[9 * XROW] = f2bf(f2.y);
    dst[10 * XROW] = f2bf(f2.z); dst[11 * XROW] = f2bf(f2.w);
    dst[12 * XROW] = f2bf(f3.x); dst[13 * XROW] = f2bf(f3.y);
    dst[14 * XROW] = f2bf(f3.z); dst[15 * XROW] = f2bf(f3.w);
  }
  __syncthreads();
  bfrag8 bf[2][4];
#pragma unroll
  for (int qs = 0; qs < 2; qs++)
#pragma unroll
    for (int kk = 0; kk < 4; kk++)
      bf[qs][kk] = *(const bfrag8*)&xb[(16 * qs + lo) * XROW + kk * 32 + g * 8];
#pragma unroll
  for (int mt6 = 0; mt6 < 6; mt6++) {
    const int rowbase = (w * 6 + mt6) * 16;
    ffrag4 d0 = {0.f, 0.f, 0.f, 0.f};
    ffrag4 d1 = {0.f, 0.f, 0.f, 0.f};
#pragma unroll
    for (int kk = 0; kk < 4; kk++) {
      bfrag8 af = *(const bfrag8*)&wqkb[(size_t)(rowbase + lo) * CC + kk * 32 + g * 8];
      d0 = __builtin_amdgcn_mfma_f32_16x16x32_bf16(af, bf[0][kk], d0, 0, 0, 0);
      d1 = __builtin_amdgcn_mfma_f32_16x16x32_bf16(af, bf[1][kk], d1, 0, 0, 0);
    }
    const int r0c = rowbase + 4 * g;
#pragma unroll
    for (int qs = 0; qs < 2; qs++) {
      const ffrag4 d = qs ? d1 : d0;
      const int na = na0 + 16 * qs;
      if (r0c < CC) {
        const int h = r0c >> 5, dd0 = r0c & 31;
        uint2 pk;
        pk.x = pk2(d[0] + t_qk[r0c] * QSCL, d[1] + t_qk[r0c + 1] * QSCL);
        pk.y = pk2(d[2] + t_qk[r0c + 2] * QSCL, d[3] + t_qk[r0c + 3] * QSCL);
        *(uint2*)&qt[((size_t)(be * HEADS + h) * NAa + na + lo) * HD + dd0] = pk;
      } else if (r0c < 2 * CC) {
        const int ch = r0c - CC, h = ch >> 5, dd0 = ch & 31;
        uint2 pk;
        pk.x = pk2(d[0] + t_qk[r0c], d[1] + t_qk[r0c + 1]);
        pk.y = pk2(d[2] + t_qk[r0c + 2], d[3] + t_qk[r0c + 3]);
        *(uint2*)&kt[((size_t)(be * HEADS + h) * NAa + na + lo) * HD + dd0] = pk;
      } else {
        const int ch0 = r0c - 2 * CC;
        const uint2 xv = *(const uint2*)&xb[(16 * qs + lo) * XROW + ch0];
        float xr[4] = {bfl(xv.x), bfh(xv.x), bfl(xv.y), bfh(xv.y)};
#pragma unroll
        for (int r = 0; r < 4; r++) {
          float y = d[r] + t_in[ch0 + r];
          vstage[(ch0 + r) * 32 + 16 * qs + lo] = f2bf(sigmoid_fast(y) * xr[r]);
        }
      }
    }
  }
  // ---- vb writeout: 128 rows x 64B, packed dword stores (vbp is 4B-aligned) ----
  __syncthreads();
  {
    const size_t vrow0 = (size_t)be * CC * NAa + na0;
    for (int i = tid; i < 2048; i += 256) {
      const int row = i >> 4, col2 = i & 15;
      *(unsigned*)&vb[vrow0 + (size_t)row * NAa + 2 * col2] =
          *(const unsigned*)&vstage[row * 32 + 2 * col2];
    }
  }
}

// ---- K2a: partial softmax denominators (M0 = 0, q pre-scaled) ----
//      64 queries x 4 key-splits per block (grid stays 800 -> occupancy kept):
//      each kf B-fragment feeds FOUR MFMAs, halving K loads + addressing again.
__global__ __launch_bounds__(256) void stats_kernel(
    const unsigned short* __restrict__ qt, const unsigned short* __restrict__ kt,
    float* __restrict__ pstats) {
  int tid = threadIdx.x;
  int h = tid >> 6, lane = tid & 63, lo = lane & 15, g = lane >> 4;
  int bid = blockIdx.x;
  int be = bid & 7;
  int rest = bid >> 3;            // 0..99
  int n0 = (rest % 25) * 64;
  int ks = rest / 25;             // 0..3
  int ts0 = (ks == 0) ? 0 : (ks == 1 ? 7 : (ks == 2 ? 13 : 19));
  int ts1 = (ks == 0) ? 7 : (ks == 1 ? 13 : (ks == 2 ? 19 : 25));

  const unsigned short* qtb = qt + (size_t)(be * HEADS + h) * NAa * HD;
  const unsigned short* ktb = kt + (size_t)(be * HEADS + h) * NAa * HD;

  bfrag8 qf[4];
#pragma unroll
  for (int qq = 0; qq < 4; qq++)
    qf[qq] = *(const bfrag8*)(qtb + (size_t)(n0 + 16 * qq + lo) * HD + g * 8);
  float sm[4][4];
#pragma unroll
  for (int qq = 0; qq < 4; qq++)
#pragma unroll
    for (int r = 0; r < 4; r++) sm[qq][r] = 0.f;

  for (int t = ts0; t < ts1; t++) {
    int m0 = t * MT;
#pragma unroll
    for (int sb = 0; sb < 4; sb++) {
      bfrag8 kf = *(const bfrag8*)(ktb + (size_t)(m0 + sb * 16 + lo) * HD + g * 8);
#pragma unroll
      for (int qq = 0; qq < 4; qq++) {
        ffrag4 z = {0.f, 0.f, 0.f, 0.f};
        ffrag4 c = __builtin_amdgcn_mfma_f32_16x16x32_bf16(qf[qq], kf, z, 0, 0, 0);
#pragma unroll
        for (int r = 0; r < 4; r++) sm[qq][r] += __builtin_amdgcn_exp2f(c[r]);
      }
    }
  }
#pragma unroll
  for (int qq = 0; qq < 4; qq++)
#pragma unroll
    for (int r = 0; r < 4; r++) {
#pragma unroll
      for (int off = 1; off <= 8; off <<= 1) sm[qq][r] += __shfl_xor(sm[qq][r], off);
    }
  if (lo == 0) {
#pragma unroll
    for (int qq = 0; qq < 4; qq++) {
      float4 s4; s4.x = sm[qq][0]; s4.y = sm[qq][1]; s4.z = sm[qq][2]; s4.w = sm[qq][3];
      *(float4*)&pstats[((size_t)(ks * 8 + be) * HEADS + h) * NAa + n0 + 16 * qq + 4 * g] = s4;
    }
  }
}

// ---- K2b: apply — R7 structure (512 thr, NB=32, single-buffered P + parity
//      halo Hb, 3-WAY key split, grid 1200). Straggler-aware split mapping:
//      the LAST 400 bids (the 176 second-round stragglers live there) get the
//      8-tile split [9,17); 9-tile splits launch first. conv carry (R10).
//      No setprio (R6). ----
__global__ __launch_bounds__(512) void apply_kernel(
    const unsigned short* __restrict__ qt, const unsigned short* __restrict__ kt,
    const unsigned short* __restrict__ vb, const float* __restrict__ pstats,
    const float* __restrict__ w_fg, const float* __restrict__ s_fg,
    const float* __restrict__ t_fg, unsigned short* __restrict__ o_part) {
  __shared__ __align__(16) unsigned short Ps[2 * PW];   // 17536 B
  __shared__ __align__(16) unsigned short A2s[2 * AW];  // 19584 B
  __shared__ __align__(16) unsigned short Hb[1024];     //  2048 B halo [par][qs][h][lo][4]
  const int tid = threadIdx.x;
  const int w = tid >> 6, lane = tid & 63, lo = lane & 15, g = lane >> 4;
  const int h = w >> 1, u = w & 1;
  const int bid = blockIdx.x;
  const int be = bid & 7;
  const int rest = bid >> 3;
  const int n0 = (rest % 50) * NB;
  const int split = rest / 50;                         // 0..2 (physical slot)
  // straggler-aware: slot 0 -> [0,9), slot 1 -> [17,26), slot 2 (last) -> [9,17)
  const int ts0 = (split == 0) ? 0 : (split == 1 ? 17 : 9);
  const int tend = (split == 0) ? 9 : (split == 1 ? 26 : 17);  // t=25 virtual tail
  const int p0 = ts0 & 1;

  const unsigned short* qtb = qt + (size_t)(be * HEADS + h) * NAa * HD;
  const unsigned short* ktb = kt + (size_t)(be * HEADS + h) * NAa * HD;
  const unsigned short* vhb = vb + (size_t)(be * CC + h * HD) * NAa;

  bfrag8 qf[2];
#pragma unroll
  for (int qs = 0; qs < 2; ++qs)
    qf[qs] = *(const bfrag8*)(qtb + (size_t)(n0 + 16 * qs + lo) * HD + g * 8);

  // conv-weight A-fragment (constant): row=lo=(ho*4+s), k=g*8+j
  bfrag8 wfrag;
  {
    const int ho = lo >> 2, s = lo & 3;
#pragma unroll
    for (int j = 0; j < 8; j++) {
      const int tp = j - s;
      float wv = (tp >= 0 && tp < 5) ? w_fg[(ho * HEADS + g) * 5 + tp] : 0.0f;
      wfrag[j] = (short)f2bf(wv);
    }
  }
  const float sfv = s_fg[g], tfv = t_fg[g];

  // -log2(denominator) per q-subtile (4 key-split partials), folded into MFMA C-in
  float linv[2];
#pragma unroll
  for (int qs = 0; qs < 2; ++qs) {
    float den = 0.f;
#pragma unroll
    for (int ks = 0; ks < 4; ++ks)
      den += pstats[((size_t)(ks * 8 + be) * HEADS + h) * NAa + n0 + 16 * qs + lo];
    linv[qs] = -__log2f(den);
  }

  ffrag4 oacc[2][2];
#pragma unroll
  for (int qs = 0; qs < 2; ++qs) {
    ffrag4 z = {0.f, 0.f, 0.f, 0.f};
    oacc[qs][0] = z; oacc[qs][1] = z;
  }

  // ---- prologue: Hb[p0] = halo for conv(ts0) ----
  if (ts0 == 0) {
    if (u == 0 && g == 0) {
      uint2 zz; zz.x = 0; zz.y = 0;
#pragma unroll
      for (int qs = 0; qs < 2; ++qs)
        *(uint2*)&Hb[HB_IDX(p0, qs, h, lo)] = zz;
    }
  } else if (u == 0) {
    // halo keys ts0*64-4..-1 from K rows ts0*64-16..-1 (g==3 lanes hold them)
    bfrag8 kf = *(const bfrag8*)(ktb + (size_t)(ts0 * MT - 16 + lo) * HD + g * 8);
#pragma unroll
    for (int qs = 0; qs < 2; ++qs) {
      ffrag4 cin = {linv[qs], linv[qs], linv[qs], linv[qs]};
      ffrag4 c = __builtin_amdgcn_mfma_f32_16x16x32_bf16(kf, qf[qs], cin, 0, 0, 0);
      if (g == 3) {
        uint2 pk;
        pk.x = pk2(__builtin_amdgcn_exp2f(c[0]), __builtin_amdgcn_exp2f(c[1]));
        pk.y = pk2(__builtin_amdgcn_exp2f(c[2]), __builtin_amdgcn_exp2f(c[3]));
        *(uint2*)&Hb[HB_IDX(p0, qs, h, lo)] = pk;
      }
    }
  }
  // ---- prologue: QK(ts0) -> Ps; sb==3/g==3 lanes also feed Hb[p0^1] ----
  {
    const int m0 = ts0 * MT;
#pragma unroll
    for (int sbi = 0; sbi < 2; sbi++) {
      const int sb = 2 * u + sbi;
      bfrag8 kf = *(const bfrag8*)(ktb + (size_t)(m0 + sb * 16 + lo) * HD + g * 8);
#pragma unroll
      for (int qs = 0; qs < 2; ++qs) {
        ffrag4 cin = {linv[qs], linv[qs], linv[qs], linv[qs]};
        ffrag4 c = __builtin_amdgcn_mfma_f32_16x16x32_bf16(kf, qf[qs], cin, 0, 0, 0);
        uint2 pk;
        pk.x = pk2(__builtin_amdgcn_exp2f(c[0]), __builtin_amdgcn_exp2f(c[1]));
        pk.y = pk2(__builtin_amdgcn_exp2f(c[2]), __builtin_amdgcn_exp2f(c[3]));
        *(uint2*)&Ps[qs * PW + h * P_HEAD + lo * P_ROW + 16 * sb + 4 * g] = pk;
        if (sb == 3 && g == 3)
          *(uint2*)&Hb[HB_IDX(p0 ^ 1, qs, h, lo)] = pk;
      }
    }
  }
  __syncthreads();

  for (int t = ts0; t < tend; t++) {
    const int m0 = t * MT;
    const int par = t & 1;
    // early V loads (k-half u) for PV(t) — shared across q-subtiles
    const bfrag8 vf0 = *(const bfrag8*)(vhb + (size_t)lo * NAa + (m0 - 2 + 32 * u + 8 * g));
    const bfrag8 vf1 = *(const bfrag8*)(vhb + (size_t)(16 + lo) * NAa + (m0 - 2 + 32 * u + 8 * g));
    const bool doqk = (t + 1 < tend);
    const bool realqk = doqk && (t + 1 < 25);
    bfrag8 kf0, kf1;
    if (realqk) {
      const int m1 = (t + 1) * MT;
      kf0 = *(const bfrag8*)(ktb + (size_t)(m1 + (2 * u) * 16 + lo) * HD + g * 8);
      kf1 = *(const bfrag8*)(ktb + (size_t)(m1 + (2 * u + 1) * 16 + lo) * HD + g * 8);
    }
    // ---- phase 1: conv(t) reads Ps/Hb -> writes A2s (carry overlapping uint2) ----
    const bool edge = (t == 0) || (t == 25);
#pragma unroll
    for (int qs = 0; qs < 2; ++qs) {
      uint2 carry;
#pragma unroll
      for (int ii = 0; ii < 2; ii++) {
        const int i = 2 * w + ii;
        cvt16 bb;
        if (ii == 0) {
          if (i == 0)
            bb.u2[0] = *(const uint2*)&Hb[HB_IDX(par, qs, g, lo)];
          else
            bb.u2[0] = *(const uint2*)&Ps[qs * PW + g * P_HEAD + lo * P_ROW + 4 * i - 4];
        } else {
          bb.u2[0] = carry;   // cell 2w+1 cols 8w..8w+3 == cell 2w's high half
        }
        bb.u2[1] = *(const uint2*)&Ps[qs * PW + g * P_HEAD + lo * P_ROW + 4 * i];
        carry = bb.u2[1];
        ffrag4 z = {0.f, 0.f, 0.f, 0.f};
        ffrag4 d = __builtin_amdgcn_mfma_f32_16x16x32_bf16(wfrag, bb.f8, z, 0, 0, 0);
        float a2v[4];
        if (edge) {
#pragma unroll
          for (int r = 0; r < 4; r++) {
            const int mp = m0 - 2 + 4 * i + r;
            float y = d[r] * sfv + tfv;
            float v = y * sigmoid_fast(y);
            a2v[r] = (mp >= 0 && mp < NAa) ? v : 0.0f;
          }
        } else {
#pragma unroll
          for (int r = 0; r < 4; r++) {
            float y = d[r] * sfv + tfv;
            a2v[r] = y * sigmoid_fast(y);
          }
        }
        uint2 pk;
        pk.x = pk2(a2v[0], a2v[1]);
        pk.y = pk2(a2v[2], a2v[3]);
        *(uint2*)&A2s[qs * AW + g * A_HEAD + lo * A_ROW + 4 * i] = pk;
      }
    }
    __syncthreads();
    // ---- phase 2: QK(t+1) -> Ps/Hb, then PV(t) reads A2s ----
    if (doqk) {
      if (realqk) {
#pragma unroll
        for (int qs = 0; qs < 2; ++qs) {
          ffrag4 cin = {linv[qs], linv[qs], linv[qs], linv[qs]};
          ffrag4 c0 = __builtin_amdgcn_mfma_f32_16x16x32_bf16(kf0, qf[qs], cin, 0, 0, 0);
          ffrag4 c1 = __builtin_amdgcn_mfma_f32_16x16x32_bf16(kf1, qf[qs], cin, 0, 0, 0);
          uint2 pk;
          pk.x = pk2(__builtin_amdgcn_exp2f(c0[0]), __builtin_amdgcn_exp2f(c0[1]));
          pk.y = pk2(__builtin_amdgcn_exp2f(c0[2]), __builtin_amdgcn_exp2f(c0[3]));
          *(uint2*)&Ps[qs * PW + h * P_HEAD + lo * P_ROW + 16 * (2 * u) + 4 * g] = pk;
          uint2 pk1;
          pk1.x = pk2(__builtin_amdgcn_exp2f(c1[0]), __builtin_amdgcn_exp2f(c1[1]));
          pk1.y = pk2(__builtin_amdgcn_exp2f(c1[2]), __builtin_amdgcn_exp2f(c1[3]));
          *(uint2*)&Ps[qs * PW + h * P_HEAD + lo * P_ROW + 16 * (2 * u + 1) + 4 * g] = pk1;
          if (u == 1 && g == 3)
            *(uint2*)&Hb[HB_IDX(par, qs, h, lo)] = pk1;   // halo for conv(t+2)
        }
      } else {
        uint2 zz; zz.x = 0; zz.y = 0;
#pragma unroll
        for (int qs = 0; qs < 2; ++qs) {
          *(uint2*)&Ps[qs * PW + h * P_HEAD + lo * P_ROW + 16 * (2 * u) + 4 * g] = zz;
          *(uint2*)&Ps[qs * PW + h * P_HEAD + lo * P_ROW + 16 * (2 * u + 1) + 4 * g] = zz;
        }
      }
    }
    // PV(t): head h, k-half u, both qsubs (V frags shared)
#pragma unroll
    for (int qs = 0; qs < 2; ++qs) {
      cvt16 av;
      av.u2[0] = *(const uint2*)&A2s[qs * AW + h * A_HEAD + lo * A_ROW + 32 * u + 8 * g];
      av.u2[1] = *(const uint2*)&A2s[qs * AW + h * A_HEAD + lo * A_ROW + 32 * u + 8 * g + 4];
      oacc[qs][0] = __builtin_amdgcn_mfma_f32_16x16x32_bf16(av.f8, vf0, oacc[qs][0], 0, 0, 0);
      oacc[qs][1] = __builtin_amdgcn_mfma_f32_16x16x32_bf16(av.f8, vf1, oacc[qs][1], 0, 0, 0);
    }
    __syncthreads();
  }

  // ---- cross-u reduction via A2s scratch, write o_part [split][be][n][c] bf16 ----
  float* scr = (float*)A2s;
  if (u == 1) {
#pragma unroll
    for (int qs = 0; qs < 2; ++qs) {
      float4 f0; f0.x = oacc[qs][0][0]; f0.y = oacc[qs][0][1]; f0.z = oacc[qs][0][2]; f0.w = oacc[qs][0][3];
      float4 f1; f1.x = oacc[qs][1][0]; f1.y = oacc[qs][1][1]; f1.z = oacc[qs][1][2]; f1.w = oacc[qs][1][3];
      *(float4*)&scr[((qs * 4 + h) * 64 + lane) * 8] = f0;
      *(float4*)&scr[((qs * 4 + h) * 64 + lane) * 8 + 4] = f1;
    }
  }
  __syncthreads();
  if (u == 0) {
#pragma unroll
    for (int qs = 0; qs < 2; ++qs) {
      const float4 f0 = *(const float4*)&scr[((qs * 4 + h) * 64 + lane) * 8];
      const float4 f1 = *(const float4*)&scr[((qs * 4 + h) * 64 + lane) * 8 + 4];
      const float fa[4] = {f0.x, f0.y, f0.z, f0.w};
      const float fb[4] = {f1.x, f1.y, f1.z, f1.w};
#pragma unroll
      for (int r = 0; r < 4; r++) {
        const size_t rowoff = ((size_t)(split * 8 + be) * NAa + n0 + 16 * qs + 4 * g + r) * CC;
        o_part[rowoff + h * HD + lo] = f2bf(oacc[qs][0][r] + fa[r]);
        o_part[rowoff + h * HD + 16 + lo] = f2bf(oacc[qs][1][r] + fb[r]);
      }
    }
  }
}

// ---- K3: out as MFMA GEMM + SiLU-gate + residual, 32 pixels/block
//      (two q-subtiles processed sequentially to keep VGPR <=128). ----
__global__ __launch_bounds__(256) void out_kernel(
    const unsigned short* __restrict__ o_part, const unsigned short* __restrict__ wob,
    const float* __restrict__ t_out, const float* __restrict__ x,
    float* __restrict__ out) {
  const int tid = threadIdx.x;
  const int w = tid >> 6, lane = tid & 63, lo = lane & 15, g = lane >> 4;
  const int blk = blockIdx.x;
  const int b = blk / 200, pt = blk - b * 200;
  const int ng0 = pt * 32;
  const int a = ng0 / NAa, na0 = ng0 - a * NAa;
  const int be = b * 4 + a;
#pragma unroll
  for (int qs = 0; qs < 2; qs++) {
    size_t orow[3];
#pragma unroll
    for (int s = 0; s < 3; s++)
      orow[s] = ((size_t)(s * 8 + be) * NAa + na0 + 16 * qs + lo) * CC;
    bfrag8 bfs[3][4];
#pragma unroll
    for (int s = 0; s < 3; s++)
#pragma unroll
      for (int kk = 0; kk < 4; kk++)
        bfs[s][kk] = *(const bfrag8*)&o_part[orow[s] + kk * 32 + g * 8];
#pragma unroll
    for (int mt2 = 0; mt2 < 2; mt2++) {
      const int rowbase = (w * 2 + mt2) * 16;
      ffrag4 d = {0.f, 0.f, 0.f, 0.f};
#pragma unroll
      for (int kk = 0; kk < 4; kk++) {
        bfrag8 af = *(const bfrag8*)&wob[(size_t)(rowbase + lo) * CC + kk * 32 + g * 8];
#pragma unroll
        for (int s = 0; s < 3; s++)
          d = __builtin_amdgcn_mfma_f32_16x16x32_bf16(af, bfs[s][kk], d, 0, 0, 0);
      }
      const int ch0 = rowbase + 4 * g;
      float ov[4] = {0.f, 0.f, 0.f, 0.f};
#pragma unroll
      for (int s = 0; s < 3; s++) {
        const uint2 q = *(const uint2*)&o_part[orow[s] + ch0];
        ov[0] += bfl(q.x); ov[1] += bfh(q.x);
        ov[2] += bfl(q.y); ov[3] += bfh(q.y);
      }
#pragma unroll
      for (int r = 0; r < 4; r++) {
        const size_t xi = ((size_t)b * CC + ch0 + r) * NN + ng0 + 16 * qs + lo;
        float y = d[r] + t_out[ch0 + r];
        out[xi] = ov[r] * sigmoid_fast(y) + x[xi];
      }
    }
  }
}

extern "C" void kernel_launch(void* const* d_in, const int* in_sizes, int n_in,
                              void* d_out, int out_size, void* d_ws, size_t ws_size,
                              hipStream_t stream) {
  const float* x    = (const float*)d_in[0];
  const float* w_qk = (const float*)d_in[1];
  const float* s_qk = (const float*)d_in[2];
  const float* t_qk = (const float*)d_in[3];
  const float* w_in = (const float*)d_in[4];
  const float* s_in = (const float*)d_in[5];
  const float* t_in = (const float*)d_in[6];
  const float* w_out = (const float*)d_in[7];
  const float* s_out = (const float*)d_in[8];
  const float* t_out = (const float*)d_in[9];
  const float* w_fg = (const float*)d_in[10];
  const float* s_fg = (const float*)d_in[11];
  const float* t_fg = (const float*)d_in[12];

  char* wsb = (char*)d_ws;
  unsigned short* o_part = (unsigned short*)wsb;               // 9,830,400 B  [3 split][be][n][c] bf16
  unsigned short* vb_raw = (unsigned short*)(wsb + 9830400);   // 3,276,864 B
  unsigned short* vbp = vb_raw + 2;
  unsigned short* qt = (unsigned short*)(wsb + 13107264);      // 3,276,800 B
  unsigned short* kt = (unsigned short*)(wsb + 16384064);      // 3,276,800 B
  unsigned short* wqkb = (unsigned short*)(wsb + 19660864);    //    98,304 B
  unsigned short* wob = (unsigned short*)(wsb + 19759168);     //    32,768 B
  float* pstats = (float*)(wsb + 19791936);                    // 3,276,800 B [4 ks][be][h][n] -> total 23,068,736 B
  float* out = (float*)d_out;

  prep_kernel<<<10, 256, 0, stream>>>(w_qk, s_qk, w_in, s_in, w_out, s_out, wqkb, wob);
  qkv_kernel<<<400, 256, 0, stream>>>(x, wqkb, t_qk, t_in, qt, kt, vbp);
  stats_kernel<<<800, 256, 0, stream>>>(qt, kt, pstats);
  apply_kernel<<<1200, 512, 0, stream>>>(qt, kt, vbp, pstats, w_fg, s_fg, t_fg, o_part);
  out_kernel<<<400, 256, 0, stream>>>(o_part, wob, t_out, x, out);
}